// Round 2
// baseline (2009.355 us; speedup 1.0000x reference)
//
#include <hip/hip_runtime.h>

#define T_TOK 8192
#define HDIM 2048
#define IDIM 1408
#define NEXP 8

#define LDK 72  // fallback (fp32-staging) path only
#define BKF 64  // fallback K-step

typedef short s16x8 __attribute__((ext_vector_type(8)));
typedef float f32x4 __attribute__((ext_vector_type(4)));
typedef unsigned short ushort_t;

__device__ __forceinline__ ushort_t f2bf(float f) {
  unsigned int u = __float_as_uint(f);
  unsigned int r = (u + 0x7fffu + ((u >> 16) & 1u)) >> 16;  // RNE
  return (ushort_t)r;
}

// async global->LDS, 16B per lane; lds base must be wave-uniform, HW adds lane*16
__device__ __forceinline__ void gll16(const void* g, void* lds) {
  __builtin_amdgcn_global_load_lds(
      (const __attribute__((address_space(1))) unsigned int*)g,
      (__attribute__((address_space(3))) unsigned int*)lds, 16, 0, 0);
}

// ---------- fp32 -> bf16 bulk cast (8 elems/thread) ----------
__global__ __launch_bounds__(256) void k_cast(const float* __restrict__ src,
                                              ushort_t* __restrict__ dst, int n8) {
  int i = blockIdx.x * blockDim.x + threadIdx.x;
  if (i < n8) {
    float4 f0 = ((const float4*)src)[(size_t)i * 2];
    float4 f1 = ((const float4*)src)[(size_t)i * 2 + 1];
    union { ushort_t us[8]; uint4 v; } p;
    p.us[0]=f2bf(f0.x); p.us[1]=f2bf(f0.y); p.us[2]=f2bf(f0.z); p.us[3]=f2bf(f0.w);
    p.us[4]=f2bf(f1.x); p.us[5]=f2bf(f1.y); p.us[6]=f2bf(f1.z); p.us[7]=f2bf(f1.w);
    ((uint4*)dst)[i] = p.v;
  }
}

// ---------- Kernel A: RMSNorm + fp32 router + top2 scatter ----------
__global__ __launch_bounds__(256) void k_rms_router(
    const float* __restrict__ x, const float* __restrict__ rmsw,
    const float* __restrict__ rw, ushort_t* __restrict__ xnorm,
    float* __restrict__ logits_out, int* __restrict__ counts,
    int* __restrict__ tokens, float* __restrict__ pairw)
{
  const int t = blockIdx.x;
  const int tid = threadIdx.x;
  const float* xr = x + (size_t)t * HDIM + tid * 8;
  float4 a = *(const float4*)xr;
  float4 b = *(const float4*)(xr + 4);
  float xi[8] = {a.x, a.y, a.z, a.w, b.x, b.y, b.z, b.w};
  float ss = 0.f;
  #pragma unroll
  for (int i = 0; i < 8; i++) ss += xi[i] * xi[i];
  #pragma unroll
  for (int o = 32; o > 0; o >>= 1) ss += __shfl_down(ss, o, 64);
  __shared__ float s_red[4];
  if ((tid & 63) == 0) s_red[tid >> 6] = ss;
  __syncthreads();
  float tot = s_red[0] + s_red[1] + s_red[2] + s_red[3];
  float rstd = rsqrtf(tot * (1.0f / HDIM) + 1e-6f);

  const float* wwp = rmsw + tid * 8;
  #pragma unroll
  for (int i = 0; i < 8; i++) xi[i] = xi[i] * rstd * wwp[i];

  union { ushort_t us[8]; uint4 v; } pk;
  #pragma unroll
  for (int i = 0; i < 8; i++) pk.us[i] = f2bf(xi[i]);
  *(uint4*)(xnorm + (size_t)t * HDIM + tid * 8) = pk.v;

  float lg[8];
  #pragma unroll
  for (int e = 0; e < 8; e++) {
    const float4* wr = (const float4*)(rw + e * HDIM + tid * 8);
    float4 w0 = wr[0], w1 = wr[1];
    lg[e] = xi[0]*w0.x + xi[1]*w0.y + xi[2]*w0.z + xi[3]*w0.w
          + xi[4]*w1.x + xi[5]*w1.y + xi[6]*w1.z + xi[7]*w1.w;
  }
  #pragma unroll
  for (int e = 0; e < 8; e++) {
    #pragma unroll
    for (int o = 32; o > 0; o >>= 1) lg[e] += __shfl_down(lg[e], o, 64);
  }
  __shared__ float s_lg[4][8];
  if ((tid & 63) == 0) {
    #pragma unroll
    for (int e = 0; e < 8; e++) s_lg[tid >> 6][e] = lg[e];
  }
  __syncthreads();
  __shared__ float s_fin[8];
  if (tid < 8) {
    float l = s_lg[0][tid] + s_lg[1][tid] + s_lg[2][tid] + s_lg[3][tid];
    logits_out[(size_t)t * NEXP + tid] = l;
    s_fin[tid] = l;
  }
  __syncthreads();
  if (tid == 0) {
    int i0 = 0;
    #pragma unroll
    for (int e = 1; e < 8; e++) if (s_fin[e] > s_fin[i0]) i0 = e;
    int i1 = (i0 == 0) ? 1 : 0;
    #pragma unroll
    for (int e = 0; e < 8; e++) if (e != i0 && s_fin[e] > s_fin[i1]) i1 = e;
    float p1 = __expf(s_fin[i1] - s_fin[i0]);
    float inv = 1.0f / (1.0f + p1);
    float w0 = inv, w1 = p1 * inv;
    int s0 = atomicAdd(&counts[i0], 1);
    tokens[i0 * T_TOK + s0] = t; pairw[i0 * T_TOK + s0] = w0;
    int s1 = atomicAdd(&counts[i1], 1);
    tokens[i1 * T_TOK + s1] = t; pairw[i1 * T_TOK + s1] = w1;
  }
}

__global__ void k_scan(const int* __restrict__ counts, int* __restrict__ basep) {
  if (threadIdx.x == 0) {
    int s = 0;
    for (int e = 0; e < NEXP; e++) { basep[e] = s; s += counts[e]; }
  }
}

// ================= bf16-weight fast path: 256^2 8-phase GEMMs =================
//
// Structure (T3+T4+T5, race-free by region liveness):
//  - 512 thr (8 waves, 2x4), tile 256x256, BK=64 as two K-halves of 32.
//  - LDS: sA/sB[2 buf][2 khalf][256 rows x 32 elems] = 128 KiB total.
//  - Per K-tile kt (par=kt&1): 4 phases {kh,mi-half}:
//      p1: reads(Ak0 h0 + B k0), stage (kt+1)Ak1 -> [par^1][1]
//      p2: reads(Ak0 h1),        stage (kt+1)Bk1, then vmcnt(8)
//      p3: reads(Ak1 h0 + B k1), stage (kt+2)Ak0 -> [par][0]   (k0 dead after p2)
//      p4: reads(Ak1 h1),        stage (kt+2)Bk0, then vmcnt(8)
//    Each phase: barrier; lgkmcnt(0)+sched_barrier (rule 18); setprio(1); 16 MFMA; setprio(0); barrier.
//    vmcnt(8) leaves exactly the 4 newest half-tiles in flight; in-order vmcnt
//    counting guarantees every half lands >=1 barrier before its first read.
//  - Swizzle: chunk ^= row&3 within each K-half (uniform 8 lanes/16B-slot ->
//    conflict-free b128); source pre-swizzled, gll16 dest linear (rule 21).

#define GEMM_PHASE(PAR, KH, H, READB, STAGE_STMT, TAIL_STMT)                         \
  {                                                                                  \
    s16x8 af[4];                                                                     \
    _Pragma("unroll") for (int j = 0; j < 4; j++) {                                  \
      const int r_ = wr * 128 + ((H) * 4 + j) * 16 + fr;                             \
      af[j] = *(const s16x8*)&sA[PAR][KH][(size_t)r_ * 32 + ((fq ^ (r_ & 3)) << 3)]; \
    }                                                                                \
    if (READB) {                                                                     \
      _Pragma("unroll") for (int n = 0; n < 4; n++) {                                \
        const int r_ = wc * 64 + n * 16 + fr;                                        \
        bfr[n] = *(const s16x8*)&sB[PAR][KH][(size_t)r_ * 32 + ((fq ^ (r_ & 3)) << 3)]; \
      }                                                                              \
    }                                                                                \
    STAGE_STMT;                                                                      \
    __builtin_amdgcn_s_barrier();                                                    \
    asm volatile("s_waitcnt lgkmcnt(0)" ::: "memory");                               \
    __builtin_amdgcn_sched_barrier(0);                                               \
    __builtin_amdgcn_s_setprio(1);                                                   \
    _Pragma("unroll") for (int j = 0; j < 4; j++)                                    \
      _Pragma("unroll") for (int n = 0; n < 4; n++)                                  \
        acc[(H) * 4 + j][n] = __builtin_amdgcn_mfma_f32_16x16x32_bf16(               \
            af[j], bfr[n], acc[(H) * 4 + j][n], 0, 0, 0);                            \
    __builtin_amdgcn_s_setprio(0);                                                   \
    TAIL_STMT;                                                                       \
    __builtin_amdgcn_s_barrier();                                                    \
  }

#define STAGE_A(P, KH, T) do {                                                       \
    gll16(aB0 + (size_t)((T) * 64 + (KH) * 32), &sA[P][KH][w * 512]);                \
    gll16(aB1 + (size_t)((T) * 64 + (KH) * 32), &sA[P][KH][4096 + w * 512]); } while (0)
#define STAGE_B(P, KH, T) do {                                                       \
    gll16(bB0 + (size_t)((T) * 64 + (KH) * 32), &sB[P][KH][w * 512]);                \
    gll16(bB1 + (size_t)((T) * 64 + (KH) * 32), &sB[P][KH][4096 + w * 512]); } while (0)

#define VMW8 asm volatile("s_waitcnt vmcnt(8)" ::: "memory")

// ---------- Kernel B: gathered gate+up GEMM + silu -> h (bf16) ----------
// Virtual-N: 256 virtual cols = 128 real cols x {gate,up} interleaved at 16.
__global__ __launch_bounds__(512) void k_gateup_bf16(
    const ushort_t* __restrict__ xnorm, const ushort_t* __restrict__ wgb,
    const ushort_t* __restrict__ wub, const int* __restrict__ tokens,
    const int* __restrict__ counts, const int* __restrict__ basep,
    ushort_t* __restrict__ hbuf)
{
  const int e = blockIdx.z;
  const int cnt = counts[e];
  const int m0 = blockIdx.x * 256;
  if (m0 >= cnt) return;
  const int r0 = blockIdx.y * 128;   // real I-column base
  const int tid = threadIdx.x;
  const int lane = tid & 63;
  const int w = tid >> 6;
  const int wr = w >> 2, wc = w & 3;
  const int fr = lane & 15, fq = lane >> 4;

  __shared__ ushort_t sA[2][2][8192];
  __shared__ ushort_t sB[2][2][8192];

  // staging map: LDS row = inst*128 + w*16 + (lane>>2); phys chunk = lane&3
  // holds logical chunk (lane&3)^(row&3)  -> pre-swizzled source
  const int srow = w * 16 + (lane >> 2);
  const int sch  = ((lane & 3) ^ ((lane >> 2) & 3)) * 8;

  const ushort_t *aB0, *aB1, *bB0, *bB1;
  {
    int rl = srow;
    int slot = (m0 + rl < cnt) ? m0 + rl : cnt - 1;
    aB0 = xnorm + (size_t)tokens[e * T_TOK + slot] * HDIM + sch;
    int nrow = r0 + ((rl >> 5) << 4) + (rl & 15);
    bB0 = (((rl >> 4) & 1) ? wub : wgb) + ((size_t)e * IDIM + nrow) * HDIM + sch;
    rl = 128 + srow;
    slot = (m0 + rl < cnt) ? m0 + rl : cnt - 1;
    aB1 = xnorm + (size_t)tokens[e * T_TOK + slot] * HDIM + sch;
    nrow = r0 + ((rl >> 5) << 4) + (rl & 15);
    bB1 = (((rl >> 4) & 1) ? wub : wgb) + ((size_t)e * IDIM + nrow) * HDIM + sch;
  }

  f32x4 acc[8][4] = {};
  const int NT = HDIM / 64;  // 32

  // prologue: t0 all 4 halves + t1 {Ak0,Bk0}; leave t1 k0 in flight
  STAGE_A(0, 0, 0); STAGE_B(0, 0, 0); STAGE_A(0, 1, 0); STAGE_B(0, 1, 0);
  STAGE_A(1, 0, 1); STAGE_B(1, 0, 1);
  asm volatile("s_waitcnt vmcnt(4)" ::: "memory");
  __builtin_amdgcn_s_barrier();

  for (int kt = 0; kt < NT; ++kt) {
    const int par = kt & 1, nxt = par ^ 1;
    s16x8 bfr[4];
    GEMM_PHASE(par, 0, 0, 1, if (kt + 1 < NT) STAGE_A(nxt, 1, kt + 1), );
    GEMM_PHASE(par, 0, 1, 0, if (kt + 1 < NT) STAGE_B(nxt, 1, kt + 1), VMW8);
    GEMM_PHASE(par, 1, 0, 1, if (kt + 2 < NT) STAGE_A(par, 0, kt + 2), );
    GEMM_PHASE(par, 1, 1, 0, if (kt + 2 < NT) STAGE_B(par, 0, kt + 2), VMW8);
  }

  // epilogue: ni even = gate, ni odd = up (same real col) -> wave-local silu
  const int hb = basep[e];
  #pragma unroll
  for (int mi = 0; mi < 8; mi++) {
    #pragma unroll
    for (int reg = 0; reg < 4; reg++) {
      const int rl = wr * 128 + mi * 16 + fq * 4 + reg;
      if (m0 + rl < cnt) {
        ushort_t* hrow = hbuf + (size_t)(hb + m0 + rl) * IDIM + r0;
        #pragma unroll
        for (int nj = 0; nj < 2; nj++) {
          float g = acc[mi][2 * nj][reg];
          float u = acc[mi][2 * nj + 1][reg];
          float hv = (g / (1.0f + __expf(-g))) * u;
          hrow[(wc * 2 + nj) * 16 + fr] = f2bf(hv);
        }
      }
    }
  }
}

// ---------- Kernel C: down GEMM + weighted atomic combine ----------
__global__ __launch_bounds__(512) void k_down_bf16(
    const ushort_t* __restrict__ hbuf, const ushort_t* __restrict__ wdb,
    const int* __restrict__ tokens, const float* __restrict__ pairw,
    const int* __restrict__ counts, const int* __restrict__ basep,
    float* __restrict__ out)
{
  const int e = blockIdx.z;
  const int cnt = counts[e];
  const int m0 = blockIdx.x * 256;
  if (m0 >= cnt) return;
  const int n0 = blockIdx.y * 256;
  const int tid = threadIdx.x;
  const int hb = basep[e];
  const int lane = tid & 63;
  const int w = tid >> 6;
  const int wr = w >> 2, wc = w & 3;
  const int fr = lane & 15, fq = lane >> 4;

  __shared__ ushort_t sA[2][2][8192];
  __shared__ ushort_t sB[2][2][8192];

  const int srow = w * 16 + (lane >> 2);
  const int sch  = ((lane & 3) ^ ((lane >> 2) & 3)) * 8;

  const ushort_t *aB0, *aB1, *bB0, *bB1;
  {
    int rl = srow;
    int slot = (m0 + rl < cnt) ? m0 + rl : cnt - 1;
    aB0 = hbuf + (size_t)(hb + slot) * IDIM + sch;
    bB0 = wdb + ((size_t)e * HDIM + n0 + rl) * IDIM + sch;
    rl = 128 + srow;
    slot = (m0 + rl < cnt) ? m0 + rl : cnt - 1;
    aB1 = hbuf + (size_t)(hb + slot) * IDIM + sch;
    bB1 = wdb + ((size_t)e * HDIM + n0 + rl) * IDIM + sch;
  }

  f32x4 acc[8][4] = {};
  const int NT = IDIM / 64;  // 22

  STAGE_A(0, 0, 0); STAGE_B(0, 0, 0); STAGE_A(0, 1, 0); STAGE_B(0, 1, 0);
  STAGE_A(1, 0, 1); STAGE_B(1, 0, 1);
  asm volatile("s_waitcnt vmcnt(4)" ::: "memory");
  __builtin_amdgcn_s_barrier();

  for (int kt = 0; kt < NT; ++kt) {
    const int par = kt & 1, nxt = par ^ 1;
    s16x8 bfr[4];
    GEMM_PHASE(par, 0, 0, 1, if (kt + 1 < NT) STAGE_A(nxt, 1, kt + 1), );
    GEMM_PHASE(par, 0, 1, 0, if (kt + 1 < NT) STAGE_B(nxt, 1, kt + 1), VMW8);
    GEMM_PHASE(par, 1, 0, 1, if (kt + 2 < NT) STAGE_A(par, 0, kt + 2), );
    GEMM_PHASE(par, 1, 1, 0, if (kt + 2 < NT) STAGE_B(par, 0, kt + 2), VMW8);
  }

  #pragma unroll
  for (int mi = 0; mi < 8; mi++) {
    #pragma unroll
    for (int reg = 0; reg < 4; reg++) {
      const int rl = wr * 128 + mi * 16 + fq * 4 + reg;
      if (m0 + rl < cnt) {
        const int tok = tokens[e * T_TOK + m0 + rl];
        const float ww = pairw[e * T_TOK + m0 + rl];
        float* orow = out + (size_t)tok * HDIM + n0;
        #pragma unroll
        for (int ni = 0; ni < 4; ni++)
          atomicAdd(&orow[wc * 64 + ni * 16 + fr], ww * acc[mi][ni][reg]);
      }
    }
  }
}

// ================= fp32-weight fallback path (round-1 kernels) =================

__global__ __launch_bounds__(256, 2) void k_gateup_f32(
    const ushort_t* __restrict__ xnorm, const float* __restrict__ wg,
    const float* __restrict__ wu, const int* __restrict__ tokens,
    const int* __restrict__ counts, const int* __restrict__ basep,
    ushort_t* __restrict__ hbuf)
{
  const int e = blockIdx.z;
  const int cnt = counts[e];
  const int m0 = blockIdx.x * 128;
  if (m0 >= cnt) return;
  const int n0 = blockIdx.y * 128;
  const int tid = threadIdx.x;

  __shared__ ushort_t As[128 * LDK];
  __shared__ ushort_t Bgs[128 * LDK];
  __shared__ ushort_t Bus[128 * LDK];

  const int r = tid >> 1;
  const int col0 = (tid & 1) * 32;
  const int slot = (m0 + r < cnt) ? (m0 + r) : (cnt - 1);
  const int tok = tokens[e * T_TOK + slot];
  const ushort_t* asrc = xnorm + (size_t)tok * HDIM + col0;
  const float* gsrc = wg + ((size_t)e * IDIM + n0 + r) * HDIM + col0;
  const float* usrc = wu + ((size_t)e * IDIM + n0 + r) * HDIM + col0;

  const int lane = tid & 63;
  const int wid = tid >> 6;
  const int wm = (wid & 1) * 64;
  const int wn = (wid >> 1) * 64;
  const int fr = lane & 15;
  const int fq = lane >> 4;

  f32x4 accg[4][4] = {};
  f32x4 accu[4][4] = {};

  for (int k0 = 0; k0 < HDIM; k0 += BKF) {
    #pragma unroll
    for (int i = 0; i < 4; i++) {
      uint4 v = *(const uint4*)(asrc + k0 + i * 8);
      *(uint4*)(&As[r * LDK + col0 + i * 8]) = v;
    }
    #pragma unroll
    for (int i = 0; i < 4; i++) {
      float4 f0 = *(const float4*)(gsrc + k0 + i * 8);
      float4 f1 = *(const float4*)(gsrc + k0 + i * 8 + 4);
      union { ushort_t us[8]; uint4 v; } p;
      p.us[0]=f2bf(f0.x); p.us[1]=f2bf(f0.y); p.us[2]=f2bf(f0.z); p.us[3]=f2bf(f0.w);
      p.us[4]=f2bf(f1.x); p.us[5]=f2bf(f1.y); p.us[6]=f2bf(f1.z); p.us[7]=f2bf(f1.w);
      *(uint4*)(&Bgs[r * LDK + col0 + i * 8]) = p.v;
    }
    #pragma unroll
    for (int i = 0; i < 4; i++) {
      float4 f0 = *(const float4*)(usrc + k0 + i * 8);
      float4 f1 = *(const float4*)(usrc + k0 + i * 8 + 4);
      union { ushort_t us[8]; uint4 v; } p;
      p.us[0]=f2bf(f0.x); p.us[1]=f2bf(f0.y); p.us[2]=f2bf(f0.z); p.us[3]=f2bf(f0.w);
      p.us[4]=f2bf(f1.x); p.us[5]=f2bf(f1.y); p.us[6]=f2bf(f1.z); p.us[7]=f2bf(f1.w);
      *(uint4*)(&Bus[r * LDK + col0 + i * 8]) = p.v;
    }
    __syncthreads();
    #pragma unroll
    for (int kk = 0; kk < BKF; kk += 32) {
      s16x8 af[4], bg[4], bu[4];
      #pragma unroll
      for (int mi = 0; mi < 4; mi++)
        af[mi] = *(const s16x8*)(&As[(wm + mi * 16 + fr) * LDK + kk + fq * 8]);
      #pragma unroll
      for (int ni = 0; ni < 4; ni++) {
        bg[ni] = *(const s16x8*)(&Bgs[(wn + ni * 16 + fr) * LDK + kk + fq * 8]);
        bu[ni] = *(const s16x8*)(&Bus[(wn + ni * 16 + fr) * LDK + kk + fq * 8]);
      }
      #pragma unroll
      for (int mi = 0; mi < 4; mi++) {
        #pragma unroll
        for (int ni = 0; ni < 4; ni++) {
          accg[mi][ni] = __builtin_amdgcn_mfma_f32_16x16x32_bf16(af[mi], bg[ni], accg[mi][ni], 0, 0, 0);
          accu[mi][ni] = __builtin_amdgcn_mfma_f32_16x16x32_bf16(af[mi], bu[ni], accu[mi][ni], 0, 0, 0);
        }
      }
    }
    __syncthreads();
  }

  const int hb = basep[e];
  #pragma unroll
  for (int mi = 0; mi < 4; mi++) {
    #pragma unroll
    for (int reg = 0; reg < 4; reg++) {
      const int rl = wm + mi * 16 + fq * 4 + reg;
      if (m0 + rl < cnt) {
        ushort_t* hrow = hbuf + (size_t)(hb + m0 + rl) * IDIM + n0;
        #pragma unroll
        for (int ni = 0; ni < 4; ni++) {
          float g = accg[mi][ni][reg];
          float u = accu[mi][ni][reg];
          float hv = (g / (1.0f + __expf(-g))) * u;
          hrow[wn + ni * 16 + fr] = f2bf(hv);
        }
      }
    }
  }
}

__global__ __launch_bounds__(256, 2) void k_down_f32(
    const ushort_t* __restrict__ hbuf, const float* __restrict__ wd,
    const int* __restrict__ tokens, const float* __restrict__ pairw,
    const int* __restrict__ counts, const int* __restrict__ basep,
    float* __restrict__ out)
{
  const int e = blockIdx.z;
  const int cnt = counts[e];
  const int m0 = blockIdx.x * 128;
  if (m0 >= cnt) return;
  const int n0 = blockIdx.y * 128;
  const int tid = threadIdx.x;
  const int hb = basep[e];

  __shared__ ushort_t As[128 * LDK];
  __shared__ ushort_t Bs[128 * LDK];

  const int r = tid >> 1;
  const int col0 = (tid & 1) * 32;
  const int slot = (m0 + r < cnt) ? (m0 + r) : (cnt - 1);
  const ushort_t* asrc = hbuf + (size_t)(hb + slot) * IDIM + col0;
  const float* bsrc = wd + ((size_t)e * HDIM + n0 + r) * IDIM + col0;

  const int lane = tid & 63;
  const int wid = tid >> 6;
  const int wm = (wid & 1) * 64;
  const int wn = (wid >> 1) * 64;
  const int fr = lane & 15;
  const int fq = lane >> 4;

  f32x4 acc[4][4] = {};

  for (int k0 = 0; k0 < IDIM; k0 += BKF) {
    #pragma unroll
    for (int i = 0; i < 4; i++) {
      uint4 v = *(const uint4*)(asrc + k0 + i * 8);
      *(uint4*)(&As[r * LDK + col0 + i * 8]) = v;
    }
    #pragma unroll
    for (int i = 0; i < 4; i++) {
      float4 f0 = *(const float4*)(bsrc + k0 + i * 8);
      float4 f1 = *(const float4*)(bsrc + k0 + i * 8 + 4);
      union { ushort_t us[8]; uint4 v; } p;
      p.us[0]=f2bf(f0.x); p.us[1]=f2bf(f0.y); p.us[2]=f2bf(f0.z); p.us[3]=f2bf(f0.w);
      p.us[4]=f2bf(f1.x); p.us[5]=f2bf(f1.y); p.us[6]=f2bf(f1.z); p.us[7]=f2bf(f1.w);
      *(uint4*)(&Bs[r * LDK + col0 + i * 8]) = p.v;
    }
    __syncthreads();
    #pragma unroll
    for (int kk = 0; kk < BKF; kk += 32) {
      s16x8 af[4], bf[4];
      #pragma unroll
      for (int mi = 0; mi < 4; mi++)
        af[mi] = *(const s16x8*)(&As[(wm + mi * 16 + fr) * LDK + kk + fq * 8]);
      #pragma unroll
      for (int ni = 0; ni < 4; ni++)
        bf[ni] = *(const s16x8*)(&Bs[(wn + ni * 16 + fr) * LDK + kk + fq * 8]);
      #pragma unroll
      for (int mi = 0; mi < 4; mi++) {
        #pragma unroll
        for (int ni = 0; ni < 4; ni++)
          acc[mi][ni] = __builtin_amdgcn_mfma_f32_16x16x32_bf16(af[mi], bf[ni], acc[mi][ni], 0, 0, 0);
      }
    }
    __syncthreads();
  }

  #pragma unroll
  for (int mi = 0; mi < 4; mi++) {
    #pragma unroll
    for (int reg = 0; reg < 4; reg++) {
      const int rl = wm + mi * 16 + fq * 4 + reg;
      if (m0 + rl < cnt) {
        const int tok = tokens[e * T_TOK + m0 + rl];
        const float ww = pairw[e * T_TOK + m0 + rl];
        float* orow = out + (size_t)tok * HDIM + n0;
        #pragma unroll
        for (int ni = 0; ni < 4; ni++)
          atomicAdd(&orow[wn + ni * 16 + fr], ww * acc[mi][ni][reg]);
      }
    }
  }
}

extern "C" void kernel_launch(void* const* d_in, const int* in_sizes, int n_in,
                              void* d_out, int out_size, void* d_ws, size_t ws_size,
                              hipStream_t stream)
{
  (void)in_sizes; (void)n_in;
  const float* x    = (const float*)d_in[0];
  const float* rmsw = (const float*)d_in[1];
  const float* rw   = (const float*)d_in[2];
  const float* wg   = (const float*)d_in[3];
  const float* wu   = (const float*)d_in[4];
  const float* wd   = (const float*)d_in[5];
  float* out = (float*)d_out;
  float* logits_out = out + (size_t)T_TOK * HDIM;

  const size_t WB = (size_t)NEXP * IDIM * HDIM * 2;   // 46,137,344 B per bf16 weight
  const size_t HB = (size_t)2 * T_TOK * IDIM * 2;     // 46,137,344 B hbuf
  const size_t XB = (size_t)T_TOK * HDIM * 2;         // 33,554,432 B xnorm
  const size_t BOOK = 1024 + 2 * (size_t)NEXP * T_TOK * 4;  // counts/basep/tokens/pairw

  char* ws = (char*)d_ws;
  int* counts  = (int*)ws;
  int* basep   = (int*)(ws + 256);
  int* tokens  = (int*)(ws + 1024);
  float* pairw = (float*)(ws + 1024 + (size_t)NEXP * T_TOK * 4);

  hipMemsetAsync(d_out, 0, (size_t)out_size * sizeof(float), stream);
  hipMemsetAsync(d_ws, 0, 512, stream);

  const size_t NEED = BOOK + HB + 2 * WB + ((WB > XB) ? WB : XB) + 4096;
  const int n8 = (int)((size_t)NEXP * IDIM * HDIM / 8);  // elems/8 per weight tensor

  if (ws_size >= NEED) {
    // fast path: bf16 weights + 8-phase GEMMs
    ushort_t* hbuf  = (ushort_t*)(ws + BOOK);
    ushort_t* wgb   = (ushort_t*)(ws + BOOK + HB);
    ushort_t* wub   = (ushort_t*)(ws + BOOK + HB + WB);
    ushort_t* xnorm = (ushort_t*)(ws + BOOK + HB + 2 * WB);
    ushort_t* wdb   = (ushort_t*)(ws + BOOK + HB + 2 * WB);  // aliases xnorm (used after)

    k_cast<<<(n8 + 255) / 256, 256, 0, stream>>>(wg, wgb, n8);
    k_cast<<<(n8 + 255) / 256, 256, 0, stream>>>(wu, wub, n8);
    k_rms_router<<<T_TOK, 256, 0, stream>>>(x, rmsw, rw, xnorm, logits_out,
                                            counts, tokens, pairw);
    k_scan<<<1, 64, 0, stream>>>(counts, basep);
    // 256 tokens x 256 virtual cols (=128 real) per block
    k_gateup_bf16<<<dim3(T_TOK / 256, (2 * IDIM) / 256, NEXP), 512, 0, stream>>>(
        xnorm, wgb, wub, tokens, counts, basep, hbuf);
    k_cast<<<(n8 + 255) / 256, 256, 0, stream>>>(wd, wdb, n8);  // overwrites xnorm (done)
    k_down_bf16<<<dim3(T_TOK / 256, HDIM / 256, NEXP), 512, 0, stream>>>(
        hbuf, wdb, tokens, pairw, counts, basep, out);
  } else {
    // fallback: round-1 fp32-staging path (~80 MB ws)
    ushort_t* xnorm = (ushort_t*)(ws + BOOK);
    ushort_t* hbuf  = (ushort_t*)(ws + BOOK + XB);

    k_rms_router<<<T_TOK, 256, 0, stream>>>(x, rmsw, rw, xnorm, logits_out,
                                            counts, tokens, pairw);
    k_scan<<<1, 64, 0, stream>>>(counts, basep);
    k_gateup_f32<<<dim3(T_TOK / 128, IDIM / 128, NEXP), 256, 0, stream>>>(
        xnorm, wg, wu, tokens, counts, basep, hbuf);
    k_down_f32<<<dim3(T_TOK / 128, HDIM / 128, NEXP), 256, 0, stream>>>(
        hbuf, wd, tokens, pairw, counts, basep, out);
  }
}

// Round 3
// 1232.954 us; speedup vs baseline: 1.6297x; 1.6297x over previous
//
#include <hip/hip_runtime.h>

#define T_TOK 8192
#define HDIM 2048
#define IDIM 1408
#define NEXP 8

#define BM 128
#define BN 128
#define BK 64
#define NTILE_MAX 136   // sum ceil(cnt_e/BM) <= 16384/128 + 8
#define LDK 72          // fallback (fp32-staging) path only

typedef short s16x8 __attribute__((ext_vector_type(8)));
typedef float f32x4 __attribute__((ext_vector_type(4)));
typedef unsigned short ushort_t;

__device__ __forceinline__ ushort_t f2bf(float f) {
  unsigned int u = __float_as_uint(f);
  unsigned int r = (u + 0x7fffu + ((u >> 16) & 1u)) >> 16;  // RNE
  return (ushort_t)r;
}

// async global->LDS, 16B per lane; lds base must be wave-uniform, HW adds lane*16
__device__ __forceinline__ void gll16(const void* g, void* lds) {
  __builtin_amdgcn_global_load_lds(
      (const __attribute__((address_space(1))) unsigned int*)g,
      (__attribute__((address_space(3))) unsigned int*)lds, 16, 0, 0);
}

// bijective XCD-chunk remap (m204): consecutive remapped ids fill one XCD
__device__ __forceinline__ int xcd_remap(int orig, int nwg) {
  const int q = nwg >> 3, r = nwg & 7;
  const int x = orig & 7, i = orig >> 3;
  return (x < r ? x * (q + 1) : r * (q + 1) + (x - r) * q) + i;
}

// ---------- fp32 -> bf16 bulk cast (8 elems/thread) ----------
__global__ __launch_bounds__(256) void k_cast(const float* __restrict__ src,
                                              ushort_t* __restrict__ dst, int n8) {
  int i = blockIdx.x * blockDim.x + threadIdx.x;
  if (i < n8) {
    float4 f0 = ((const float4*)src)[(size_t)i * 2];
    float4 f1 = ((const float4*)src)[(size_t)i * 2 + 1];
    union { ushort_t us[8]; uint4 v; } p;
    p.us[0]=f2bf(f0.x); p.us[1]=f2bf(f0.y); p.us[2]=f2bf(f0.z); p.us[3]=f2bf(f0.w);
    p.us[4]=f2bf(f1.x); p.us[5]=f2bf(f1.y); p.us[6]=f2bf(f1.z); p.us[7]=f2bf(f1.w);
    ((uint4*)dst)[i] = p.v;
  }
}

// ---------- Kernel A: RMSNorm + fp32 router + top2 scatter ----------
__global__ __launch_bounds__(256) void k_rms_router(
    const float* __restrict__ x, const float* __restrict__ rmsw,
    const float* __restrict__ rw, ushort_t* __restrict__ xnorm,
    float* __restrict__ logits_out, int* __restrict__ counts,
    int* __restrict__ tokens, float* __restrict__ pairw,
    int* __restrict__ ranks)
{
  const int t = blockIdx.x;
  const int tid = threadIdx.x;
  const float* xr = x + (size_t)t * HDIM + tid * 8;
  float4 a = *(const float4*)xr;
  float4 b = *(const float4*)(xr + 4);
  float xi[8] = {a.x, a.y, a.z, a.w, b.x, b.y, b.z, b.w};
  float ss = 0.f;
  #pragma unroll
  for (int i = 0; i < 8; i++) ss += xi[i] * xi[i];
  #pragma unroll
  for (int o = 32; o > 0; o >>= 1) ss += __shfl_down(ss, o, 64);
  __shared__ float s_red[4];
  if ((tid & 63) == 0) s_red[tid >> 6] = ss;
  __syncthreads();
  float tot = s_red[0] + s_red[1] + s_red[2] + s_red[3];
  float rstd = rsqrtf(tot * (1.0f / HDIM) + 1e-6f);

  const float* wwp = rmsw + tid * 8;
  #pragma unroll
  for (int i = 0; i < 8; i++) xi[i] = xi[i] * rstd * wwp[i];

  union { ushort_t us[8]; uint4 v; } pk;
  #pragma unroll
  for (int i = 0; i < 8; i++) pk.us[i] = f2bf(xi[i]);
  *(uint4*)(xnorm + (size_t)t * HDIM + tid * 8) = pk.v;

  float lg[8];
  #pragma unroll
  for (int e = 0; e < 8; e++) {
    const float4* wr = (const float4*)(rw + e * HDIM + tid * 8);
    float4 w0 = wr[0], w1 = wr[1];
    lg[e] = xi[0]*w0.x + xi[1]*w0.y + xi[2]*w0.z + xi[3]*w0.w
          + xi[4]*w1.x + xi[5]*w1.y + xi[6]*w1.z + xi[7]*w1.w;
  }
  #pragma unroll
  for (int e = 0; e < 8; e++) {
    #pragma unroll
    for (int o = 32; o > 0; o >>= 1) lg[e] += __shfl_down(lg[e], o, 64);
  }
  __shared__ float s_lg[4][8];
  if ((tid & 63) == 0) {
    #pragma unroll
    for (int e = 0; e < 8; e++) s_lg[tid >> 6][e] = lg[e];
  }
  __syncthreads();
  __shared__ float s_fin[8];
  if (tid < 8) {
    float l = s_lg[0][tid] + s_lg[1][tid] + s_lg[2][tid] + s_lg[3][tid];
    logits_out[(size_t)t * NEXP + tid] = l;
    s_fin[tid] = l;
  }
  __syncthreads();
  if (tid == 0) {
    int i0 = 0;
    #pragma unroll
    for (int e = 1; e < 8; e++) if (s_fin[e] > s_fin[i0]) i0 = e;
    int i1 = (i0 == 0) ? 1 : 0;
    #pragma unroll
    for (int e = 0; e < 8; e++) if (e != i0 && s_fin[e] > s_fin[i1]) i1 = e;
    float p1 = __expf(s_fin[i1] - s_fin[i0]);
    float inv = 1.0f / (1.0f + p1);
    float w0 = inv, w1 = p1 * inv;
    int s0 = atomicAdd(&counts[i0], 1);
    tokens[i0 * T_TOK + s0] = t; pairw[i0 * T_TOK + s0] = w0; ranks[i0 * T_TOK + s0] = 0;
    int s1 = atomicAdd(&counts[i1], 1);
    tokens[i1 * T_TOK + s1] = t; pairw[i1 * T_TOK + s1] = w1; ranks[i1 * T_TOK + s1] = 1;
  }
}

// prefix-scan + M-tile table (e, m0) over all experts
__global__ void k_scan(const int* __restrict__ counts, int* __restrict__ basep,
                       int* __restrict__ tile_e, int* __restrict__ tile_m,
                       int* __restrict__ ntile) {
  if (threadIdx.x == 0) {
    int s = 0, nt = 0;
    for (int e = 0; e < NEXP; e++) {
      basep[e] = s;
      for (int m0 = 0; m0 < counts[e]; m0 += BM) { tile_e[nt] = e; tile_m[nt] = m0; nt++; }
      s += counts[e];
    }
    *ntile = nt;
  }
}

// ================= bf16-weight fast path =================

// ---------- Kernel B: gathered gate+up GEMM + silu -> h (bf16) ----------
// Virtual-N: 128 virtual cols = 64 real cols x {gate,up} interleaved at 16.
// M-tiles come from the tile table (no dead z-grid); flat (tile,panel) grid is
// XCD-remapped so all tiles sharing a weight panel land on one XCD's L2.
__global__ __launch_bounds__(256, 4) void k_gateup_bf16(
    const ushort_t* __restrict__ xnorm, const ushort_t* __restrict__ wgb,
    const ushort_t* __restrict__ wub, const int* __restrict__ tokens,
    const int* __restrict__ counts, const int* __restrict__ basep,
    const int* __restrict__ tile_e, const int* __restrict__ tile_m,
    const int* __restrict__ ntile, ushort_t* __restrict__ hbuf)
{
  const int nwg = gridDim.x * gridDim.y;
  int flat = blockIdx.x + gridDim.x * blockIdx.y;
  flat = xcd_remap(flat, nwg);
  const int bx = flat % gridDim.x;
  const int by = flat / gridDim.x;
  if (bx >= *ntile) return;
  const int e = tile_e[bx];
  const int m0 = tile_m[bx];
  const int cnt = counts[e];
  const int r0 = by * 64;   // real I-column base (64 real cols/block)
  const int tid = threadIdx.x;

  __shared__ ushort_t As[BM * BK];   // unpadded: required by global_load_lds
  __shared__ ushort_t Bs[BN * BK];   // virtual-N tile (gate/up interleaved)

  const int lane = tid & 63;
  const int w = tid >> 6;
  // staging map: instr i covers LDS bytes (w*4+i)*1024 + lane*16
  // -> row = (w*4+i)*8 + (lane>>3); source chunk XOR-swizzled by row&7
  const int srow = lane >> 3;
  const int scol = ((lane & 7) ^ srow) * 8;

  const ushort_t* agp[4]; const ushort_t* bgp[4];
  #pragma unroll
  for (int i = 0; i < 4; i++) {
    const int rl = (w * 4 + i) * 8 + srow;
    const int slot = (m0 + rl < cnt) ? (m0 + rl) : (cnt - 1);
    const int tok = tokens[e * T_TOK + slot];
    agp[i] = xnorm + (size_t)tok * HDIM + scol;
    const int nrow = r0 + ((rl >> 5) << 4) + (rl & 15);   // real weight row
    const ushort_t* wsrc = ((rl >> 4) & 1) ? wub : wgb;   // 0=gate,1=up
    bgp[i] = wsrc + ((size_t)e * IDIM + nrow) * HDIM + scol;
  }

  const int wm = (w & 1) * 64;
  const int wn = (w >> 1) * 64;
  const int fr = lane & 15;
  const int fq = lane >> 4;
  const int sx = fr & 7;            // read-side XOR (row&7 == fr&7)

  f32x4 acc[4][4] = {};

  for (int k0 = 0; k0 < HDIM; k0 += BK) {
    #pragma unroll
    for (int i = 0; i < 4; i++) gll16(agp[i] + k0, &As[(w * 4 + i) * 512]);
    #pragma unroll
    for (int i = 0; i < 4; i++) gll16(bgp[i] + k0, &Bs[(w * 4 + i) * 512]);
    __syncthreads();
    #pragma unroll
    for (int kk = 0; kk < BK; kk += 32) {
      const int c0 = kk >> 3;       // base 16B-chunk index of this k-slice
      s16x8 af[4], bf[4];
      #pragma unroll
      for (int mi = 0; mi < 4; mi++)
        af[mi] = *(const s16x8*)(&As[(wm + mi * 16 + fr) * BK + (((c0 + fq) ^ sx) << 3)]);
      #pragma unroll
      for (int ni = 0; ni < 4; ni++)
        bf[ni] = *(const s16x8*)(&Bs[(wn + ni * 16 + fr) * BK + (((c0 + fq) ^ sx) << 3)]);
      #pragma unroll
      for (int mi = 0; mi < 4; mi++) {
        #pragma unroll
        for (int ni = 0; ni < 4; ni++)
          acc[mi][ni] = __builtin_amdgcn_mfma_f32_16x16x32_bf16(af[mi], bf[ni], acc[mi][ni], 0, 0, 0);
      }
    }
    __syncthreads();
  }

  // epilogue: ni even = gate, ni odd = up (same real col) -> wave-local silu
  const int hb = basep[e];
  #pragma unroll
  for (int mi = 0; mi < 4; mi++) {
    #pragma unroll
    for (int reg = 0; reg < 4; reg++) {
      const int rl = wm + mi * 16 + fq * 4 + reg;
      if (m0 + rl < cnt) {
        ushort_t* hrow = hbuf + (size_t)(hb + m0 + rl) * IDIM + r0 + (wn >> 1);
        #pragma unroll
        for (int nj = 0; nj < 2; nj++) {
          float g = acc[mi][2 * nj][reg];
          float u = acc[mi][2 * nj + 1][reg];
          float hv = (g / (1.0f + __expf(-g))) * u;
          hrow[nj * 16 + fr] = f2bf(hv);
        }
      }
    }
  }
}

// ---------- Kernel C: down GEMM, rank-split plain stores (NO atomics) ----------
// rank0 rows -> out directly; rank1 rows -> out_b; k_combine adds them.
__global__ __launch_bounds__(256, 4) void k_down_bf16(
    const ushort_t* __restrict__ hbuf, const ushort_t* __restrict__ wdb,
    const int* __restrict__ tokens, const float* __restrict__ pairw,
    const int* __restrict__ ranks, const int* __restrict__ counts,
    const int* __restrict__ basep, const int* __restrict__ tile_e,
    const int* __restrict__ tile_m, const int* __restrict__ ntile,
    float* __restrict__ out, float* __restrict__ out_b)
{
  const int nwg = gridDim.x * gridDim.y;
  int flat = blockIdx.x + gridDim.x * blockIdx.y;
  flat = xcd_remap(flat, nwg);
  const int bx = flat % gridDim.x;
  const int by = flat / gridDim.x;
  if (bx >= *ntile) return;
  const int e = tile_e[bx];
  const int m0 = tile_m[bx];
  const int cnt = counts[e];
  const int n0 = by * BN;
  const int tid = threadIdx.x;
  const int hb = basep[e];

  __shared__ ushort_t As[BM * BK];
  __shared__ ushort_t Bs[BN * BK];

  const int lane = tid & 63;
  const int w = tid >> 6;
  const int srow = lane >> 3;
  const int scol = ((lane & 7) ^ srow) * 8;   // bothsides swizzle, source side

  const ushort_t* agp[4]; const ushort_t* bgp[4];
  #pragma unroll
  for (int i = 0; i < 4; i++) {
    const int rl = (w * 4 + i) * 8 + srow;
    const int slot = (m0 + rl < cnt) ? (m0 + rl) : (cnt - 1);
    agp[i] = hbuf + (size_t)(hb + slot) * IDIM + scol;
    bgp[i] = wdb + ((size_t)e * HDIM + n0 + rl) * IDIM + scol;
  }

  const int wm = (w & 1) * 64;
  const int wn = (w >> 1) * 64;
  const int fr = lane & 15;
  const int fq = lane >> 4;
  const int sx = fr & 7;

  f32x4 acc[4][4] = {};

  for (int k0 = 0; k0 < IDIM; k0 += BK) {
    #pragma unroll
    for (int i = 0; i < 4; i++) gll16(agp[i] + k0, &As[(w * 4 + i) * 512]);
    #pragma unroll
    for (int i = 0; i < 4; i++) gll16(bgp[i] + k0, &Bs[(w * 4 + i) * 512]);
    __syncthreads();
    #pragma unroll
    for (int kk = 0; kk < BK; kk += 32) {
      const int c0 = kk >> 3;
      s16x8 af[4], bf[4];
      #pragma unroll
      for (int mi = 0; mi < 4; mi++)
        af[mi] = *(const s16x8*)(&As[(wm + mi * 16 + fr) * BK + (((c0 + fq) ^ sx) << 3)]);
      #pragma unroll
      for (int ni = 0; ni < 4; ni++)
        bf[ni] = *(const s16x8*)(&Bs[(wn + ni * 16 + fr) * BK + (((c0 + fq) ^ sx) << 3)]);
      #pragma unroll
      for (int mi = 0; mi < 4; mi++) {
        #pragma unroll
        for (int ni = 0; ni < 4; ni++)
          acc[mi][ni] = __builtin_amdgcn_mfma_f32_16x16x32_bf16(af[mi], bf[ni], acc[mi][ni], 0, 0, 0);
      }
    }
    __syncthreads();
  }

  #pragma unroll
  for (int mi = 0; mi < 4; mi++) {
    #pragma unroll
    for (int reg = 0; reg < 4; reg++) {
      const int rl = wm + mi * 16 + fq * 4 + reg;
      if (m0 + rl < cnt) {
        const int idx = e * T_TOK + m0 + rl;
        const int tok = tokens[idx];
        const float ww = pairw[idx];
        float* obase = ranks[idx] ? out_b : out;
        float* orow = obase + (size_t)tok * HDIM + n0;
        #pragma unroll
        for (int ni = 0; ni < 4; ni++)
          orow[wn + ni * 16 + fr] = ww * acc[mi][ni][reg];
      }
    }
  }
}

// ---------- Kernel D: out += out_b (both fully written) ----------
__global__ __launch_bounds__(256) void k_combine(float* __restrict__ out,
                                                 const float* __restrict__ outb, int n4) {
  int i = blockIdx.x * blockDim.x + threadIdx.x;
  const int stride = gridDim.x * blockDim.x;
  for (; i < n4; i += stride) {
    float4 a = ((const float4*)out)[i];
    float4 b = ((const float4*)outb)[i];
    a.x += b.x; a.y += b.y; a.z += b.z; a.w += b.w;
    ((float4*)out)[i] = a;
  }
}

// ================= fp32-weight fallback path (round-1 kernels) =================

__global__ __launch_bounds__(256, 2) void k_gateup_f32(
    const ushort_t* __restrict__ xnorm, const float* __restrict__ wg,
    const float* __restrict__ wu, const int* __restrict__ tokens,
    const int* __restrict__ counts, const int* __restrict__ basep,
    ushort_t* __restrict__ hbuf)
{
  const int e = blockIdx.z;
  const int cnt = counts[e];
  const int m0 = blockIdx.x * BM;
  if (m0 >= cnt) return;
  const int n0 = blockIdx.y * BN;
  const int tid = threadIdx.x;

  __shared__ ushort_t As[BM * LDK];
  __shared__ ushort_t Bgs[BN * LDK];
  __shared__ ushort_t Bus[BN * LDK];

  const int r = tid >> 1;
  const int col0 = (tid & 1) * 32;
  const int slot = (m0 + r < cnt) ? (m0 + r) : (cnt - 1);
  const int tok = tokens[e * T_TOK + slot];
  const ushort_t* asrc = xnorm + (size_t)tok * HDIM + col0;
  const float* gsrc = wg + ((size_t)e * IDIM + n0 + r) * HDIM + col0;
  const float* usrc = wu + ((size_t)e * IDIM + n0 + r) * HDIM + col0;

  const int lane = tid & 63;
  const int wid = tid >> 6;
  const int wm = (wid & 1) * 64;
  const int wn = (wid >> 1) * 64;
  const int fr = lane & 15;
  const int fq = lane >> 4;

  f32x4 accg[4][4] = {};
  f32x4 accu[4][4] = {};

  for (int k0 = 0; k0 < HDIM; k0 += BK) {
    #pragma unroll
    for (int i = 0; i < 4; i++) {
      uint4 v = *(const uint4*)(asrc + k0 + i * 8);
      *(uint4*)(&As[r * LDK + col0 + i * 8]) = v;
    }
    #pragma unroll
    for (int i = 0; i < 4; i++) {
      float4 f0 = *(const float4*)(gsrc + k0 + i * 8);
      float4 f1 = *(const float4*)(gsrc + k0 + i * 8 + 4);
      union { ushort_t us[8]; uint4 v; } p;
      p.us[0]=f2bf(f0.x); p.us[1]=f2bf(f0.y); p.us[2]=f2bf(f0.z); p.us[3]=f2bf(f0.w);
      p.us[4]=f2bf(f1.x); p.us[5]=f2bf(f1.y); p.us[6]=f2bf(f1.z); p.us[7]=f2bf(f1.w);
      *(uint4*)(&Bgs[r * LDK + col0 + i * 8]) = p.v;
    }
    #pragma unroll
    for (int i = 0; i < 4; i++) {
      float4 f0 = *(const float4*)(usrc + k0 + i * 8);
      float4 f1 = *(const float4*)(usrc + k0 + i * 8 + 4);
      union { ushort_t us[8]; uint4 v; } p;
      p.us[0]=f2bf(f0.x); p.us[1]=f2bf(f0.y); p.us[2]=f2bf(f0.z); p.us[3]=f2bf(f0.w);
      p.us[4]=f2bf(f1.x); p.us[5]=f2bf(f1.y); p.us[6]=f2bf(f1.z); p.us[7]=f2bf(f1.w);
      *(uint4*)(&Bus[r * LDK + col0 + i * 8]) = p.v;
    }
    __syncthreads();
    #pragma unroll
    for (int kk = 0; kk < BK; kk += 32) {
      s16x8 af[4], bg[4], bu[4];
      #pragma unroll
      for (int mi = 0; mi < 4; mi++)
        af[mi] = *(const s16x8*)(&As[(wm + mi * 16 + fr) * LDK + kk + fq * 8]);
      #pragma unroll
      for (int ni = 0; ni < 4; ni++) {
        bg[ni] = *(const s16x8*)(&Bgs[(wn + ni * 16 + fr) * LDK + kk + fq * 8]);
        bu[ni] = *(const s16x8*)(&Bus[(wn + ni * 16 + fr) * LDK + kk + fq * 8]);
      }
      #pragma unroll
      for (int mi = 0; mi < 4; mi++) {
        #pragma unroll
        for (int ni = 0; ni < 4; ni++) {
          accg[mi][ni] = __builtin_amdgcn_mfma_f32_16x16x32_bf16(af[mi], bg[ni], accg[mi][ni], 0, 0, 0);
          accu[mi][ni] = __builtin_amdgcn_mfma_f32_16x16x32_bf16(af[mi], bu[ni], accu[mi][ni], 0, 0, 0);
        }
      }
    }
    __syncthreads();
  }

  const int hb = basep[e];
  #pragma unroll
  for (int mi = 0; mi < 4; mi++) {
    #pragma unroll
    for (int reg = 0; reg < 4; reg++) {
      const int rl = wm + mi * 16 + fq * 4 + reg;
      if (m0 + rl < cnt) {
        ushort_t* hrow = hbuf + (size_t)(hb + m0 + rl) * IDIM + n0;
        #pragma unroll
        for (int ni = 0; ni < 4; ni++) {
          float g = accg[mi][ni][reg];
          float u = accu[mi][ni][reg];
          float hv = (g / (1.0f + __expf(-g))) * u;
          hrow[wn + ni * 16 + fr] = f2bf(hv);
        }
      }
    }
  }
}

__global__ __launch_bounds__(256, 2) void k_down_f32(
    const ushort_t* __restrict__ hbuf, const float* __restrict__ wd,
    const int* __restrict__ tokens, const float* __restrict__ pairw,
    const int* __restrict__ counts, const int* __restrict__ basep,
    float* __restrict__ out)
{
  const int e = blockIdx.z;
  const int cnt = counts[e];
  const int m0 = blockIdx.x * BM;
  if (m0 >= cnt) return;
  const int n0 = blockIdx.y * BN;
  const int tid = threadIdx.x;
  const int hb = basep[e];

  __shared__ ushort_t As[BM * LDK];
  __shared__ ushort_t Bs[BN * LDK];

  const int r = tid >> 1;
  const int col0 = (tid & 1) * 32;
  const int slot = (m0 + r < cnt) ? (m0 + r) : (cnt - 1);
  const ushort_t* asrc = hbuf + (size_t)(hb + slot) * IDIM + col0;
  const float* bsrc = wd + ((size_t)e * HDIM + n0 + r) * IDIM + col0;

  const int lane = tid & 63;
  const int wid = tid >> 6;
  const int wm = (wid & 1) * 64;
  const int wn = (wid >> 1) * 64;
  const int fr = lane & 15;
  const int fq = lane >> 4;

  f32x4 acc[4][4] = {};

  for (int k0 = 0; k0 < IDIM; k0 += BK) {
    #pragma unroll
    for (int i = 0; i < 4; i++) {
      uint4 v = *(const uint4*)(asrc + k0 + i * 8);
      *(uint4*)(&As[r * LDK + col0 + i * 8]) = v;
    }
    #pragma unroll
    for (int i = 0; i < 4; i++) {
      float4 f0 = *(const float4*)(bsrc + k0 + i * 8);
      float4 f1 = *(const float4*)(bsrc + k0 + i * 8 + 4);
      union { ushort_t us[8]; uint4 v; } p;
      p.us[0]=f2bf(f0.x); p.us[1]=f2bf(f0.y); p.us[2]=f2bf(f0.z); p.us[3]=f2bf(f0.w);
      p.us[4]=f2bf(f1.x); p.us[5]=f2bf(f1.y); p.us[6]=f2bf(f1.z); p.us[7]=f2bf(f1.w);
      *(uint4*)(&Bs[r * LDK + col0 + i * 8]) = p.v;
    }
    __syncthreads();
    #pragma unroll
    for (int kk = 0; kk < BK; kk += 32) {
      s16x8 af[4], bf[4];
      #pragma unroll
      for (int mi = 0; mi < 4; mi++)
        af[mi] = *(const s16x8*)(&As[(wm + mi * 16 + fr) * LDK + kk + fq * 8]);
      #pragma unroll
      for (int ni = 0; ni < 4; ni++)
        bf[ni] = *(const s16x8*)(&Bs[(wn + ni * 16 + fr) * LDK + kk + fq * 8]);
      #pragma unroll
      for (int mi = 0; mi < 4; mi++) {
        #pragma unroll
        for (int ni = 0; ni < 4; ni++)
          acc[mi][ni] = __builtin_amdgcn_mfma_f32_16x16x32_bf16(af[mi], bf[ni], acc[mi][ni], 0, 0, 0);
      }
    }
    __syncthreads();
  }

  #pragma unroll
  for (int mi = 0; mi < 4; mi++) {
    #pragma unroll
    for (int reg = 0; reg < 4; reg++) {
      const int rl = wm + mi * 16 + fq * 4 + reg;
      if (m0 + rl < cnt) {
        const int tok = tokens[e * T_TOK + m0 + rl];
        const float ww = pairw[e * T_TOK + m0 + rl];
        float* orow = out + (size_t)tok * HDIM + n0;
        #pragma unroll
        for (int ni = 0; ni < 4; ni++)
          atomicAdd(&orow[wn + ni * 16 + fr], ww * acc[mi][ni][reg]);
      }
    }
  }
}

extern "C" void kernel_launch(void* const* d_in, const int* in_sizes, int n_in,
                              void* d_out, int out_size, void* d_ws, size_t ws_size,
                              hipStream_t stream)
{
  (void)in_sizes; (void)n_in;
  const float* x    = (const float*)d_in[0];
  const float* rmsw = (const float*)d_in[1];
  const float* rw   = (const float*)d_in[2];
  const float* wg   = (const float*)d_in[3];
  const float* wu   = (const float*)d_in[4];
  const float* wd   = (const float*)d_in[5];
  float* out = (float*)d_out;
  float* logits_out = out + (size_t)T_TOK * HDIM;

  const size_t WB = (size_t)NEXP * IDIM * HDIM * 2;   // 46,137,344 B per bf16 weight
  const size_t HB = (size_t)2 * T_TOK * IDIM * 2;     // 46,137,344 B hbuf
  const size_t XB = (size_t)T_TOK * HDIM * 2;         // 33,554,432 B xnorm
  const size_t BOOK = 2048 + 3 * (size_t)NEXP * T_TOK * 4;  // counts/basep/tiles/tokens/pairw/ranks

  char* ws = (char*)d_ws;
  int* counts  = (int*)ws;
  int* basep   = (int*)(ws + 256);
  int* ntile   = (int*)(ws + 320);
  int* tile_e  = (int*)(ws + 384);                       // 136*4 B
  int* tile_m  = (int*)(ws + 1024);                      // 136*4 B
  int* tokens  = (int*)(ws + 2048);
  float* pairw = (float*)(ws + 2048 + (size_t)NEXP * T_TOK * 4);
  int* ranks   = (int*)(ws + 2048 + 2 * (size_t)NEXP * T_TOK * 4);

  hipMemsetAsync(d_ws, 0, 512, stream);

  const size_t NEED = BOOK + HB + 2 * WB + ((WB > XB) ? WB : XB) + 4096;
  const int n8 = (int)((size_t)NEXP * IDIM * HDIM / 8);  // elems/8 per weight tensor

  if (ws_size >= NEED) {
    // fast path: bf16 weights + global_load_lds + rank-split combine (no atomics)
    ushort_t* hbuf  = (ushort_t*)(ws + BOOK);
    ushort_t* wgb   = (ushort_t*)(ws + BOOK + HB);
    ushort_t* wub   = (ushort_t*)(ws + BOOK + HB + WB);
    ushort_t* xnorm = (ushort_t*)(ws + BOOK + HB + 2 * WB);
    ushort_t* wdb   = (ushort_t*)(ws + BOOK + HB + 2 * WB);  // aliases xnorm (used after)
    float* out_b    = (float*)(ws + BOOK + HB);              // overlays wgb/wub (dead in down phase); 67MB <= 92MB

    k_cast<<<(n8 + 255) / 256, 256, 0, stream>>>(wg, wgb, n8);
    k_cast<<<(n8 + 255) / 256, 256, 0, stream>>>(wu, wub, n8);
    k_rms_router<<<T_TOK, 256, 0, stream>>>(x, rmsw, rw, xnorm, logits_out,
                                            counts, tokens, pairw, ranks);
    k_scan<<<1, 64, 0, stream>>>(counts, basep, tile_e, tile_m, ntile);
    // tile table x 22 virtual-N panels (64 real I-cols each)
    k_gateup_bf16<<<dim3(NTILE_MAX, IDIM / 64), 256, 0, stream>>>(
        xnorm, wgb, wub, tokens, counts, basep, tile_e, tile_m, ntile, hbuf);
    k_cast<<<(n8 + 255) / 256, 256, 0, stream>>>(wd, wdb, n8);  // overwrites xnorm (done)
    k_down_bf16<<<dim3(NTILE_MAX, HDIM / BN), 256, 0, stream>>>(
        hbuf, wdb, tokens, pairw, ranks, counts, basep, tile_e, tile_m, ntile,
        out, out_b);
    k_combine<<<2048, 256, 0, stream>>>(out, out_b, (int)((size_t)T_TOK * HDIM / 4));
  } else {
    // fallback: round-1 fp32-staging path (~80 MB ws)
    ushort_t* xnorm = (ushort_t*)(ws + BOOK);
    ushort_t* hbuf  = (ushort_t*)(ws + BOOK + XB);

    hipMemsetAsync(d_out, 0, (size_t)out_size * sizeof(float), stream);
    k_rms_router<<<T_TOK, 256, 0, stream>>>(x, rmsw, rw, xnorm, logits_out,
                                            counts, tokens, pairw, ranks);
    k_scan<<<1, 64, 0, stream>>>(counts, basep, tile_e, tile_m, ntile);
    k_gateup_f32<<<dim3(T_TOK / BM, IDIM / BN, NEXP), 256, 0, stream>>>(
        xnorm, wg, wu, tokens, counts, basep, hbuf);
    k_down_f32<<<dim3(T_TOK / BM, HDIM / BN, NEXP), 256, 0, stream>>>(
        hbuf, wd, tokens, pairw, counts, basep, out);
  }
}

// Round 4
// 924.907 us; speedup vs baseline: 2.1725x; 1.3331x over previous
//
#include <hip/hip_runtime.h>

#define T_TOK 8192
#define HDIM 2048
#define IDIM 1408
#define NEXP 8

#define BM 128
#define BN 128
#define BK 64
#define NTILE_MAX 136   // sum ceil(cnt_e/BM) <= 16384/128 + 8
#define LDK 72          // fallback (fp32-staging) path only

typedef short s16x8 __attribute__((ext_vector_type(8)));
typedef float f32x4 __attribute__((ext_vector_type(4)));
typedef unsigned short ushort_t;

__device__ __forceinline__ ushort_t f2bf(float f) {
  unsigned int u = __float_as_uint(f);
  unsigned int r = (u + 0x7fffu + ((u >> 16) & 1u)) >> 16;  // RNE
  return (ushort_t)r;
}

// async global->LDS, 16B per lane; lds base must be wave-uniform, HW adds lane*16
__device__ __forceinline__ void gll16(const void* g, void* lds) {
  __builtin_amdgcn_global_load_lds(
      (const __attribute__((address_space(1))) unsigned int*)g,
      (__attribute__((address_space(3))) unsigned int*)lds, 16, 0, 0);
}

// ---------- fp32 -> bf16 bulk cast (8 elems/thread) ----------
__global__ __launch_bounds__(256) void k_cast(const float* __restrict__ src,
                                              ushort_t* __restrict__ dst, int n8) {
  int i = blockIdx.x * blockDim.x + threadIdx.x;
  if (i < n8) {
    float4 f0 = ((const float4*)src)[(size_t)i * 2];
    float4 f1 = ((const float4*)src)[(size_t)i * 2 + 1];
    union { ushort_t us[8]; uint4 v; } p;
    p.us[0]=f2bf(f0.x); p.us[1]=f2bf(f0.y); p.us[2]=f2bf(f0.z); p.us[3]=f2bf(f0.w);
    p.us[4]=f2bf(f1.x); p.us[5]=f2bf(f1.y); p.us[6]=f2bf(f1.z); p.us[7]=f2bf(f1.w);
    ((uint4*)dst)[i] = p.v;
  }
}

// ---------- Kernel A: RMSNorm + fp32 router + top2 scatter ----------
__global__ __launch_bounds__(256) void k_rms_router(
    const float* __restrict__ x, const float* __restrict__ rmsw,
    const float* __restrict__ rw, ushort_t* __restrict__ xnorm,
    float* __restrict__ logits_out, int* __restrict__ counts,
    int* __restrict__ tokens, float* __restrict__ pairw,
    int* __restrict__ ranks)
{
  const int t = blockIdx.x;
  const int tid = threadIdx.x;
  const float* xr = x + (size_t)t * HDIM + tid * 8;
  float4 a = *(const float4*)xr;
  float4 b = *(const float4*)(xr + 4);
  float xi[8] = {a.x, a.y, a.z, a.w, b.x, b.y, b.z, b.w};
  float ss = 0.f;
  #pragma unroll
  for (int i = 0; i < 8; i++) ss += xi[i] * xi[i];
  #pragma unroll
  for (int o = 32; o > 0; o >>= 1) ss += __shfl_down(ss, o, 64);
  __shared__ float s_red[4];
  if ((tid & 63) == 0) s_red[tid >> 6] = ss;
  __syncthreads();
  float tot = s_red[0] + s_red[1] + s_red[2] + s_red[3];
  float rstd = rsqrtf(tot * (1.0f / HDIM) + 1e-6f);

  const float* wwp = rmsw + tid * 8;
  #pragma unroll
  for (int i = 0; i < 8; i++) xi[i] = xi[i] * rstd * wwp[i];

  union { ushort_t us[8]; uint4 v; } pk;
  #pragma unroll
  for (int i = 0; i < 8; i++) pk.us[i] = f2bf(xi[i]);
  *(uint4*)(xnorm + (size_t)t * HDIM + tid * 8) = pk.v;

  float lg[8];
  #pragma unroll
  for (int e = 0; e < 8; e++) {
    const float4* wr = (const float4*)(rw + e * HDIM + tid * 8);
    float4 w0 = wr[0], w1 = wr[1];
    lg[e] = xi[0]*w0.x + xi[1]*w0.y + xi[2]*w0.z + xi[3]*w0.w
          + xi[4]*w1.x + xi[5]*w1.y + xi[6]*w1.z + xi[7]*w1.w;
  }
  #pragma unroll
  for (int e = 0; e < 8; e++) {
    #pragma unroll
    for (int o = 32; o > 0; o >>= 1) lg[e] += __shfl_down(lg[e], o, 64);
  }
  __shared__ float s_lg[4][8];
  if ((tid & 63) == 0) {
    #pragma unroll
    for (int e = 0; e < 8; e++) s_lg[tid >> 6][e] = lg[e];
  }
  __syncthreads();
  __shared__ float s_fin[8];
  if (tid < 8) {
    float l = s_lg[0][tid] + s_lg[1][tid] + s_lg[2][tid] + s_lg[3][tid];
    logits_out[(size_t)t * NEXP + tid] = l;
    s_fin[tid] = l;
  }
  __syncthreads();
  if (tid == 0) {
    int i0 = 0;
    #pragma unroll
    for (int e = 1; e < 8; e++) if (s_fin[e] > s_fin[i0]) i0 = e;
    int i1 = (i0 == 0) ? 1 : 0;
    #pragma unroll
    for (int e = 0; e < 8; e++) if (e != i0 && s_fin[e] > s_fin[i1]) i1 = e;
    float p1 = __expf(s_fin[i1] - s_fin[i0]);
    float inv = 1.0f / (1.0f + p1);
    float w0 = inv, w1 = p1 * inv;
    int s0 = atomicAdd(&counts[i0], 1);
    tokens[i0 * T_TOK + s0] = t; pairw[i0 * T_TOK + s0] = w0; ranks[i0 * T_TOK + s0] = 0;
    int s1 = atomicAdd(&counts[i1], 1);
    tokens[i1 * T_TOK + s1] = t; pairw[i1 * T_TOK + s1] = w1; ranks[i1 * T_TOK + s1] = 1;
  }
}

// prefix-scan + M-tile table (e, m0) over all experts
__global__ void k_scan(const int* __restrict__ counts, int* __restrict__ basep,
                       int* __restrict__ tile_e, int* __restrict__ tile_m,
                       int* __restrict__ ntile) {
  if (threadIdx.x == 0) {
    int s = 0, nt = 0;
    for (int e = 0; e < NEXP; e++) {
      basep[e] = s;
      for (int m0 = 0; m0 < counts[e]; m0 += BM) { tile_e[nt] = e; tile_m[nt] = m0; nt++; }
      s += counts[e];
    }
    *ntile = nt;
  }
}

// ================= bf16-weight fast path =================

// ---------- Kernel B: gathered gate+up GEMM + silu -> h (bf16) ----------
// Virtual-N: 128 virtual cols = 64 real cols x {gate,up} interleaved at 16.
// launch_bounds(256,3): VGPR 72 + AGPR 64 = 136 < 512/3 cap -> NO spill.
// (256,4) capped regs at 128 total -> in-loop scratch spill, +1.3 GB HBM traffic
// measured in round 3. Do not raise without checking scratch.
__global__ __launch_bounds__(256, 3) void k_gateup_bf16(
    const ushort_t* __restrict__ xnorm, const ushort_t* __restrict__ wgb,
    const ushort_t* __restrict__ wub, const int* __restrict__ tokens,
    const int* __restrict__ counts, const int* __restrict__ basep,
    const int* __restrict__ tile_e, const int* __restrict__ tile_m,
    const int* __restrict__ ntile, ushort_t* __restrict__ hbuf)
{
  const int bx = blockIdx.x;
  if (bx >= *ntile) return;
  const int e = tile_e[bx];
  const int m0 = tile_m[bx];
  const int cnt = counts[e];
  const int r0 = blockIdx.y * 64;   // real I-column base (64 real cols/block)
  const int tid = threadIdx.x;

  __shared__ ushort_t As[BM * BK];   // unpadded: required by global_load_lds
  __shared__ ushort_t Bs[BN * BK];   // virtual-N tile (gate/up interleaved)

  const int lane = tid & 63;
  const int w = tid >> 6;
  // staging map: instr i covers LDS bytes (w*4+i)*1024 + lane*16
  // -> row = (w*4+i)*8 + (lane>>3); source chunk XOR-swizzled by row&7
  const int srow = lane >> 3;
  const int scol = ((lane & 7) ^ srow) * 8;

  const ushort_t* agp[4]; const ushort_t* bgp[4];
  #pragma unroll
  for (int i = 0; i < 4; i++) {
    const int rl = (w * 4 + i) * 8 + srow;
    const int slot = (m0 + rl < cnt) ? (m0 + rl) : (cnt - 1);
    const int tok = tokens[e * T_TOK + slot];
    agp[i] = xnorm + (size_t)tok * HDIM + scol;
    const int nrow = r0 + ((rl >> 5) << 4) + (rl & 15);   // real weight row
    const ushort_t* wsrc = ((rl >> 4) & 1) ? wub : wgb;   // 0=gate,1=up
    bgp[i] = wsrc + ((size_t)e * IDIM + nrow) * HDIM + scol;
  }

  const int wm = (w & 1) * 64;
  const int wn = (w >> 1) * 64;
  const int fr = lane & 15;
  const int fq = lane >> 4;
  const int sx = fr & 7;            // read-side XOR (row&7 == fr&7)

  f32x4 acc[4][4] = {};

  for (int k0 = 0; k0 < HDIM; k0 += BK) {
    #pragma unroll
    for (int i = 0; i < 4; i++) gll16(agp[i] + k0, &As[(w * 4 + i) * 512]);
    #pragma unroll
    for (int i = 0; i < 4; i++) gll16(bgp[i] + k0, &Bs[(w * 4 + i) * 512]);
    __syncthreads();
    #pragma unroll
    for (int kk = 0; kk < BK; kk += 32) {
      const int c0 = kk >> 3;       // base 16B-chunk index of this k-slice
      s16x8 af[4], bf[4];
      #pragma unroll
      for (int mi = 0; mi < 4; mi++)
        af[mi] = *(const s16x8*)(&As[(wm + mi * 16 + fr) * BK + (((c0 + fq) ^ sx) << 3)]);
      #pragma unroll
      for (int ni = 0; ni < 4; ni++)
        bf[ni] = *(const s16x8*)(&Bs[(wn + ni * 16 + fr) * BK + (((c0 + fq) ^ sx) << 3)]);
      #pragma unroll
      for (int mi = 0; mi < 4; mi++) {
        #pragma unroll
        for (int ni = 0; ni < 4; ni++)
          acc[mi][ni] = __builtin_amdgcn_mfma_f32_16x16x32_bf16(af[mi], bf[ni], acc[mi][ni], 0, 0, 0);
      }
    }
    __syncthreads();
  }

  // epilogue: ni even = gate, ni odd = up (same real col) -> wave-local silu
  const int hb = basep[e];
  #pragma unroll
  for (int mi = 0; mi < 4; mi++) {
    #pragma unroll
    for (int reg = 0; reg < 4; reg++) {
      const int rl = wm + mi * 16 + fq * 4 + reg;
      if (m0 + rl < cnt) {
        ushort_t* hrow = hbuf + (size_t)(hb + m0 + rl) * IDIM + r0 + (wn >> 1);
        #pragma unroll
        for (int nj = 0; nj < 2; nj++) {
          float g = acc[mi][2 * nj][reg];
          float u = acc[mi][2 * nj + 1][reg];
          float hv = (g / (1.0f + __expf(-g))) * u;
          hrow[nj * 16 + fr] = f2bf(hv);
        }
      }
    }
  }
}

// ---------- Kernel C: down GEMM, rank-split plain stores (NO atomics) ----------
// rank0 rows -> out directly; rank1 rows -> out_b; k_combine adds them.
__global__ __launch_bounds__(256, 3) void k_down_bf16(
    const ushort_t* __restrict__ hbuf, const ushort_t* __restrict__ wdb,
    const int* __restrict__ tokens, const float* __restrict__ pairw,
    const int* __restrict__ ranks, const int* __restrict__ counts,
    const int* __restrict__ basep, const int* __restrict__ tile_e,
    const int* __restrict__ tile_m, const int* __restrict__ ntile,
    float* __restrict__ out, float* __restrict__ out_b)
{
  const int bx = blockIdx.x;
  if (bx >= *ntile) return;
  const int e = tile_e[bx];
  const int m0 = tile_m[bx];
  const int cnt = counts[e];
  const int n0 = blockIdx.y * BN;
  const int tid = threadIdx.x;
  const int hb = basep[e];

  __shared__ ushort_t As[BM * BK];
  __shared__ ushort_t Bs[BN * BK];

  const int lane = tid & 63;
  const int w = tid >> 6;
  const int srow = lane >> 3;
  const int scol = ((lane & 7) ^ srow) * 8;   // bothsides swizzle, source side

  const ushort_t* agp[4]; const ushort_t* bgp[4];
  #pragma unroll
  for (int i = 0; i < 4; i++) {
    const int rl = (w * 4 + i) * 8 + srow;
    const int slot = (m0 + rl < cnt) ? (m0 + rl) : (cnt - 1);
    agp[i] = hbuf + (size_t)(hb + slot) * IDIM + scol;
    bgp[i] = wdb + ((size_t)e * HDIM + n0 + rl) * IDIM + scol;
  }

  const int wm = (w & 1) * 64;
  const int wn = (w >> 1) * 64;
  const int fr = lane & 15;
  const int fq = lane >> 4;
  const int sx = fr & 7;

  f32x4 acc[4][4] = {};

  for (int k0 = 0; k0 < IDIM; k0 += BK) {
    #pragma unroll
    for (int i = 0; i < 4; i++) gll16(agp[i] + k0, &As[(w * 4 + i) * 512]);
    #pragma unroll
    for (int i = 0; i < 4; i++) gll16(bgp[i] + k0, &Bs[(w * 4 + i) * 512]);
    __syncthreads();
    #pragma unroll
    for (int kk = 0; kk < BK; kk += 32) {
      const int c0 = kk >> 3;
      s16x8 af[4], bf[4];
      #pragma unroll
      for (int mi = 0; mi < 4; mi++)
        af[mi] = *(const s16x8*)(&As[(wm + mi * 16 + fr) * BK + (((c0 + fq) ^ sx) << 3)]);
      #pragma unroll
      for (int ni = 0; ni < 4; ni++)
        bf[ni] = *(const s16x8*)(&Bs[(wn + ni * 16 + fr) * BK + (((c0 + fq) ^ sx) << 3)]);
      #pragma unroll
      for (int mi = 0; mi < 4; mi++) {
        #pragma unroll
        for (int ni = 0; ni < 4; ni++)
          acc[mi][ni] = __builtin_amdgcn_mfma_f32_16x16x32_bf16(af[mi], bf[ni], acc[mi][ni], 0, 0, 0);
      }
    }
    __syncthreads();
  }

  #pragma unroll
  for (int mi = 0; mi < 4; mi++) {
    #pragma unroll
    for (int reg = 0; reg < 4; reg++) {
      const int rl = wm + mi * 16 + fq * 4 + reg;
      if (m0 + rl < cnt) {
        const int idx = e * T_TOK + m0 + rl;
        const int tok = tokens[idx];
        const float ww = pairw[idx];
        float* obase = ranks[idx] ? out_b : out;
        float* orow = obase + (size_t)tok * HDIM + n0;
        #pragma unroll
        for (int ni = 0; ni < 4; ni++)
          orow[wn + ni * 16 + fr] = ww * acc[mi][ni][reg];
      }
    }
  }
}

// ---------- Kernel D: out += out_b (both fully written) ----------
__global__ __launch_bounds__(256) void k_combine(float* __restrict__ out,
                                                 const float* __restrict__ outb, int n4) {
  int i = blockIdx.x * blockDim.x + threadIdx.x;
  const int stride = gridDim.x * blockDim.x;
  for (; i < n4; i += stride) {
    float4 a = ((const float4*)out)[i];
    float4 b = ((const float4*)outb)[i];
    a.x += b.x; a.y += b.y; a.z += b.z; a.w += b.w;
    ((float4*)out)[i] = a;
  }
}

// ================= fp32-weight fallback path (round-1 kernels) =================

__global__ __launch_bounds__(256, 2) void k_gateup_f32(
    const ushort_t* __restrict__ xnorm, const float* __restrict__ wg,
    const float* __restrict__ wu, const int* __restrict__ tokens,
    const int* __restrict__ counts, const int* __restrict__ basep,
    ushort_t* __restrict__ hbuf)
{
  const int e = blockIdx.z;
  const int cnt = counts[e];
  const int m0 = blockIdx.x * BM;
  if (m0 >= cnt) return;
  const int n0 = blockIdx.y * BN;
  const int tid = threadIdx.x;

  __shared__ ushort_t As[BM * LDK];
  __shared__ ushort_t Bgs[BN * LDK];
  __shared__ ushort_t Bus[BN * LDK];

  const int r = tid >> 1;
  const int col0 = (tid & 1) * 32;
  const int slot = (m0 + r < cnt) ? (m0 + r) : (cnt - 1);
  const int tok = tokens[e * T_TOK + slot];
  const ushort_t* asrc = xnorm + (size_t)tok * HDIM + col0;
  const float* gsrc = wg + ((size_t)e * IDIM + n0 + r) * HDIM + col0;
  const float* usrc = wu + ((size_t)e * IDIM + n0 + r) * HDIM + col0;

  const int lane = tid & 63;
  const int wid = tid >> 6;
  const int wm = (wid & 1) * 64;
  const int wn = (wid >> 1) * 64;
  const int fr = lane & 15;
  const int fq = lane >> 4;

  f32x4 accg[4][4] = {};
  f32x4 accu[4][4] = {};

  for (int k0 = 0; k0 < HDIM; k0 += BK) {
    #pragma unroll
    for (int i = 0; i < 4; i++) {
      uint4 v = *(const uint4*)(asrc + k0 + i * 8);
      *(uint4*)(&As[r * LDK + col0 + i * 8]) = v;
    }
    #pragma unroll
    for (int i = 0; i < 4; i++) {
      float4 f0 = *(const float4*)(gsrc + k0 + i * 8);
      float4 f1 = *(const float4*)(gsrc + k0 + i * 8 + 4);
      union { ushort_t us[8]; uint4 v; } p;
      p.us[0]=f2bf(f0.x); p.us[1]=f2bf(f0.y); p.us[2]=f2bf(f0.z); p.us[3]=f2bf(f0.w);
      p.us[4]=f2bf(f1.x); p.us[5]=f2bf(f1.y); p.us[6]=f2bf(f1.z); p.us[7]=f2bf(f1.w);
      *(uint4*)(&Bgs[r * LDK + col0 + i * 8]) = p.v;
    }
    #pragma unroll
    for (int i = 0; i < 4; i++) {
      float4 f0 = *(const float4*)(usrc + k0 + i * 8);
      float4 f1 = *(const float4*)(usrc + k0 + i * 8 + 4);
      union { ushort_t us[8]; uint4 v; } p;
      p.us[0]=f2bf(f0.x); p.us[1]=f2bf(f0.y); p.us[2]=f2bf(f0.z); p.us[3]=f2bf(f0.w);
      p.us[4]=f2bf(f1.x); p.us[5]=f2bf(f1.y); p.us[6]=f2bf(f1.z); p.us[7]=f2bf(f1.w);
      *(uint4*)(&Bus[r * LDK + col0 + i * 8]) = p.v;
    }
    __syncthreads();
    #pragma unroll
    for (int kk = 0; kk < BK; kk += 32) {
      s16x8 af[4], bg[4], bu[4];
      #pragma unroll
      for (int mi = 0; mi < 4; mi++)
        af[mi] = *(const s16x8*)(&As[(wm + mi * 16 + fr) * LDK + kk + fq * 8]);
      #pragma unroll
      for (int ni = 0; ni < 4; ni++) {
        bg[ni] = *(const s16x8*)(&Bgs[(wn + ni * 16 + fr) * LDK + kk + fq * 8]);
        bu[ni] = *(const s16x8*)(&Bus[(wn + ni * 16 + fr) * LDK + kk + fq * 8]);
      }
      #pragma unroll
      for (int mi = 0; mi < 4; mi++) {
        #pragma unroll
        for (int ni = 0; ni < 4; ni++) {
          accg[mi][ni] = __builtin_amdgcn_mfma_f32_16x16x32_bf16(af[mi], bg[ni], accg[mi][ni], 0, 0, 0);
          accu[mi][ni] = __builtin_amdgcn_mfma_f32_16x16x32_bf16(af[mi], bu[ni], accu[mi][ni], 0, 0, 0);
        }
      }
    }
    __syncthreads();
  }

  const int hb = basep[e];
  #pragma unroll
  for (int mi = 0; mi < 4; mi++) {
    #pragma unroll
    for (int reg = 0; reg < 4; reg++) {
      const int rl = wm + mi * 16 + fq * 4 + reg;
      if (m0 + rl < cnt) {
        ushort_t* hrow = hbuf + (size_t)(hb + m0 + rl) * IDIM + n0;
        #pragma unroll
        for (int ni = 0; ni < 4; ni++) {
          float g = accg[mi][ni][reg];
          float u = accu[mi][ni][reg];
          float hv = (g / (1.0f + __expf(-g))) * u;
          hrow[wn + ni * 16 + fr] = f2bf(hv);
        }
      }
    }
  }
}

__global__ __launch_bounds__(256, 2) void k_down_f32(
    const ushort_t* __restrict__ hbuf, const float* __restrict__ wd,
    const int* __restrict__ tokens, const float* __restrict__ pairw,
    const int* __restrict__ counts, const int* __restrict__ basep,
    float* __restrict__ out)
{
  const int e = blockIdx.z;
  const int cnt = counts[e];
  const int m0 = blockIdx.x * BM;
  if (m0 >= cnt) return;
  const int n0 = blockIdx.y * BN;
  const int tid = threadIdx.x;
  const int hb = basep[e];

  __shared__ ushort_t As[BM * LDK];
  __shared__ ushort_t Bs[BN * LDK];

  const int r = tid >> 1;
  const int col0 = (tid & 1) * 32;
  const int slot = (m0 + r < cnt) ? (m0 + r) : (cnt - 1);
  const ushort_t* asrc = hbuf + (size_t)(hb + slot) * IDIM + col0;
  const float* bsrc = wd + ((size_t)e * HDIM + n0 + r) * IDIM + col0;

  const int lane = tid & 63;
  const int wid = tid >> 6;
  const int wm = (wid & 1) * 64;
  const int wn = (wid >> 1) * 64;
  const int fr = lane & 15;
  const int fq = lane >> 4;

  f32x4 acc[4][4] = {};

  for (int k0 = 0; k0 < IDIM; k0 += BK) {
    #pragma unroll
    for (int i = 0; i < 4; i++) {
      uint4 v = *(const uint4*)(asrc + k0 + i * 8);
      *(uint4*)(&As[r * LDK + col0 + i * 8]) = v;
    }
    #pragma unroll
    for (int i = 0; i < 4; i++) {
      float4 f0 = *(const float4*)(bsrc + k0 + i * 8);
      float4 f1 = *(const float4*)(bsrc + k0 + i * 8 + 4);
      union { ushort_t us[8]; uint4 v; } p;
      p.us[0]=f2bf(f0.x); p.us[1]=f2bf(f0.y); p.us[2]=f2bf(f0.z); p.us[3]=f2bf(f0.w);
      p.us[4]=f2bf(f1.x); p.us[5]=f2bf(f1.y); p.us[6]=f2bf(f1.z); p.us[7]=f2bf(f1.w);
      *(uint4*)(&Bs[r * LDK + col0 + i * 8]) = p.v;
    }
    __syncthreads();
    #pragma unroll
    for (int kk = 0; kk < BK; kk += 32) {
      s16x8 af[4], bf[4];
      #pragma unroll
      for (int mi = 0; mi < 4; mi++)
        af[mi] = *(const s16x8*)(&As[(wm + mi * 16 + fr) * LDK + kk + fq * 8]);
      #pragma unroll
      for (int ni = 0; ni < 4; ni++)
        bf[ni] = *(const s16x8*)(&Bs[(wn + ni * 16 + fr) * LDK + kk + fq * 8]);
      #pragma unroll
      for (int mi = 0; mi < 4; mi++) {
        #pragma unroll
        for (int ni = 0; ni < 4; ni++)
          acc[mi][ni] = __builtin_amdgcn_mfma_f32_16x16x32_bf16(af[mi], bf[ni], acc[mi][ni], 0, 0, 0);
      }
    }
    __syncthreads();
  }

  #pragma unroll
  for (int mi = 0; mi < 4; mi++) {
    #pragma unroll
    for (int reg = 0; reg < 4; reg++) {
      const int rl = wm + mi * 16 + fq * 4 + reg;
      if (m0 + rl < cnt) {
        const int tok = tokens[e * T_TOK + m0 + rl];
        const float ww = pairw[e * T_TOK + m0 + rl];
        float* orow = out + (size_t)tok * HDIM + n0;
        #pragma unroll
        for (int ni = 0; ni < 4; ni++)
          atomicAdd(&orow[wn + ni * 16 + fr], ww * acc[mi][ni][reg]);
      }
    }
  }
}

extern "C" void kernel_launch(void* const* d_in, const int* in_sizes, int n_in,
                              void* d_out, int out_size, void* d_ws, size_t ws_size,
                              hipStream_t stream)
{
  (void)in_sizes; (void)n_in;
  const float* x    = (const float*)d_in[0];
  const float* rmsw = (const float*)d_in[1];
  const float* rw   = (const float*)d_in[2];
  const float* wg   = (const float*)d_in[3];
  const float* wu   = (const float*)d_in[4];
  const float* wd   = (const float*)d_in[5];
  float* out = (float*)d_out;
  float* logits_out = out + (size_t)T_TOK * HDIM;

  const size_t WB = (size_t)NEXP * IDIM * HDIM * 2;   // 46,137,344 B per bf16 weight
  const size_t HB = (size_t)2 * T_TOK * IDIM * 2;     // 46,137,344 B hbuf
  const size_t XB = (size_t)T_TOK * HDIM * 2;         // 33,554,432 B xnorm
  const size_t BOOK = 2048 + 3 * (size_t)NEXP * T_TOK * 4;  // counts/basep/tiles/tokens/pairw/ranks

  char* ws = (char*)d_ws;
  int* counts  = (int*)ws;
  int* basep   = (int*)(ws + 256);
  int* ntile   = (int*)(ws + 320);
  int* tile_e  = (int*)(ws + 384);                       // 136*4 B
  int* tile_m  = (int*)(ws + 1024);                      // 136*4 B
  int* tokens  = (int*)(ws + 2048);
  float* pairw = (float*)(ws + 2048 + (size_t)NEXP * T_TOK * 4);
  int* ranks   = (int*)(ws + 2048 + 2 * (size_t)NEXP * T_TOK * 4);

  hipMemsetAsync(d_ws, 0, 512, stream);

  const size_t NEED = BOOK + HB + 2 * WB + ((WB > XB) ? WB : XB) + 4096;
  const int n8 = (int)((size_t)NEXP * IDIM * HDIM / 8);  // elems/8 per weight tensor

  if (ws_size >= NEED) {
    // fast path: bf16 weights + global_load_lds + rank-split combine (no atomics)
    ushort_t* hbuf  = (ushort_t*)(ws + BOOK);
    ushort_t* wgb   = (ushort_t*)(ws + BOOK + HB);
    ushort_t* wub   = (ushort_t*)(ws + BOOK + HB + WB);
    ushort_t* xnorm = (ushort_t*)(ws + BOOK + HB + 2 * WB);
    ushort_t* wdb   = (ushort_t*)(ws + BOOK + HB + 2 * WB);  // aliases xnorm (used after)
    float* out_b    = (float*)(ws + BOOK + HB);              // overlays wgb/wub (dead in down phase); 67MB <= 92MB

    k_cast<<<(n8 + 255) / 256, 256, 0, stream>>>(wg, wgb, n8);
    k_cast<<<(n8 + 255) / 256, 256, 0, stream>>>(wu, wub, n8);
    k_rms_router<<<T_TOK, 256, 0, stream>>>(x, rmsw, rw, xnorm, logits_out,
                                            counts, tokens, pairw, ranks);
    k_scan<<<1, 64, 0, stream>>>(counts, basep, tile_e, tile_m, ntile);
    // tile table x 22 virtual-N panels (64 real I-cols each)
    k_gateup_bf16<<<dim3(NTILE_MAX, IDIM / 64), 256, 0, stream>>>(
        xnorm, wgb, wub, tokens, counts, basep, tile_e, tile_m, ntile, hbuf);
    k_cast<<<(n8 + 255) / 256, 256, 0, stream>>>(wd, wdb, n8);  // overwrites xnorm (done)
    k_down_bf16<<<dim3(NTILE_MAX, HDIM / BN), 256, 0, stream>>>(
        hbuf, wdb, tokens, pairw, ranks, counts, basep, tile_e, tile_m, ntile,
        out, out_b);
    k_combine<<<2048, 256, 0, stream>>>(out, out_b, (int)((size_t)T_TOK * HDIM / 4));
  } else {
    // fallback: round-1 fp32-staging path (~80 MB ws)
    ushort_t* xnorm = (ushort_t*)(ws + BOOK);
    ushort_t* hbuf  = (ushort_t*)(ws + BOOK + XB);

    hipMemsetAsync(d_out, 0, (size_t)out_size * sizeof(float), stream);
    k_rms_router<<<T_TOK, 256, 0, stream>>>(x, rmsw, rw, xnorm, logits_out,
                                            counts, tokens, pairw, ranks);
    k_scan<<<1, 64, 0, stream>>>(counts, basep, tile_e, tile_m, ntile);
    k_gateup_f32<<<dim3(T_TOK / BM, IDIM / BN, NEXP), 256, 0, stream>>>(
        xnorm, wg, wu, tokens, counts, basep, hbuf);
    k_down_f32<<<dim3(T_TOK / BM, HDIM / BN, NEXP), 256, 0, stream>>>(
        hbuf, wd, tokens, pairw, counts, basep, out);
  }
}

// Round 5
// 872.888 us; speedup vs baseline: 2.3020x; 1.0596x over previous
//
#include <hip/hip_runtime.h>

#define T_TOK 8192
#define HDIM 2048
#define IDIM 1408
#define NEXP 8

#define BM 128
#define BN 128
#define BK 64
#define NTILE_MAX 136   // sum ceil(cnt_e/BM) <= 16384/128 + 8
#define LDK 72          // fallback (fp32-staging) path only

typedef short s16x8 __attribute__((ext_vector_type(8)));
typedef float f32x4 __attribute__((ext_vector_type(4)));
typedef unsigned short ushort_t;

__device__ __forceinline__ ushort_t f2bf(float f) {
  unsigned int u = __float_as_uint(f);
  unsigned int r = (u + 0x7fffu + ((u >> 16) & 1u)) >> 16;  // RNE
  return (ushort_t)r;
}

// async global->LDS, 16B per lane; lds base must be wave-uniform, HW adds lane*16
__device__ __forceinline__ void gll16(const void* g, void* lds) {
  __builtin_amdgcn_global_load_lds(
      (const __attribute__((address_space(1))) unsigned int*)g,
      (__attribute__((address_space(3))) unsigned int*)lds, 16, 0, 0);
}

// ---------- fp32 -> bf16 bulk cast (8 elems/thread) ----------
__global__ __launch_bounds__(256) void k_cast(const float* __restrict__ src,
                                              ushort_t* __restrict__ dst, int n8) {
  int i = blockIdx.x * blockDim.x + threadIdx.x;
  if (i < n8) {
    float4 f0 = ((const float4*)src)[(size_t)i * 2];
    float4 f1 = ((const float4*)src)[(size_t)i * 2 + 1];
    union { ushort_t us[8]; uint4 v; } p;
    p.us[0]=f2bf(f0.x); p.us[1]=f2bf(f0.y); p.us[2]=f2bf(f0.z); p.us[3]=f2bf(f0.w);
    p.us[4]=f2bf(f1.x); p.us[5]=f2bf(f1.y); p.us[6]=f2bf(f1.z); p.us[7]=f2bf(f1.w);
    ((uint4*)dst)[i] = p.v;
  }
}

// ---------- Kernel A: RMSNorm + fp32 router + top2 scatter ----------
__global__ __launch_bounds__(256) void k_rms_router(
    const float* __restrict__ x, const float* __restrict__ rmsw,
    const float* __restrict__ rw, ushort_t* __restrict__ xnorm,
    float* __restrict__ logits_out, int* __restrict__ counts,
    int* __restrict__ tokens, float* __restrict__ pairw,
    int* __restrict__ ranks)
{
  const int t = blockIdx.x;
  const int tid = threadIdx.x;
  const float* xr = x + (size_t)t * HDIM + tid * 8;
  float4 a = *(const float4*)xr;
  float4 b = *(const float4*)(xr + 4);
  float xi[8] = {a.x, a.y, a.z, a.w, b.x, b.y, b.z, b.w};
  float ss = 0.f;
  #pragma unroll
  for (int i = 0; i < 8; i++) ss += xi[i] * xi[i];
  #pragma unroll
  for (int o = 32; o > 0; o >>= 1) ss += __shfl_down(ss, o, 64);
  __shared__ float s_red[4];
  if ((tid & 63) == 0) s_red[tid >> 6] = ss;
  __syncthreads();
  float tot = s_red[0] + s_red[1] + s_red[2] + s_red[3];
  float rstd = rsqrtf(tot * (1.0f / HDIM) + 1e-6f);

  const float* wwp = rmsw + tid * 8;
  #pragma unroll
  for (int i = 0; i < 8; i++) xi[i] = xi[i] * rstd * wwp[i];

  union { ushort_t us[8]; uint4 v; } pk;
  #pragma unroll
  for (int i = 0; i < 8; i++) pk.us[i] = f2bf(xi[i]);
  *(uint4*)(xnorm + (size_t)t * HDIM + tid * 8) = pk.v;

  float lg[8];
  #pragma unroll
  for (int e = 0; e < 8; e++) {
    const float4* wr = (const float4*)(rw + e * HDIM + tid * 8);
    float4 w0 = wr[0], w1 = wr[1];
    lg[e] = xi[0]*w0.x + xi[1]*w0.y + xi[2]*w0.z + xi[3]*w0.w
          + xi[4]*w1.x + xi[5]*w1.y + xi[6]*w1.z + xi[7]*w1.w;
  }
  #pragma unroll
  for (int e = 0; e < 8; e++) {
    #pragma unroll
    for (int o = 32; o > 0; o >>= 1) lg[e] += __shfl_down(lg[e], o, 64);
  }
  __shared__ float s_lg[4][8];
  if ((tid & 63) == 0) {
    #pragma unroll
    for (int e = 0; e < 8; e++) s_lg[tid >> 6][e] = lg[e];
  }
  __syncthreads();
  __shared__ float s_fin[8];
  if (tid < 8) {
    float l = s_lg[0][tid] + s_lg[1][tid] + s_lg[2][tid] + s_lg[3][tid];
    logits_out[(size_t)t * NEXP + tid] = l;
    s_fin[tid] = l;
  }
  __syncthreads();
  if (tid == 0) {
    int i0 = 0;
    #pragma unroll
    for (int e = 1; e < 8; e++) if (s_fin[e] > s_fin[i0]) i0 = e;
    int i1 = (i0 == 0) ? 1 : 0;
    #pragma unroll
    for (int e = 0; e < 8; e++) if (e != i0 && s_fin[e] > s_fin[i1]) i1 = e;
    float p1 = __expf(s_fin[i1] - s_fin[i0]);
    float inv = 1.0f / (1.0f + p1);
    float w0 = inv, w1 = p1 * inv;
    int s0 = atomicAdd(&counts[i0], 1);
    tokens[i0 * T_TOK + s0] = t; pairw[i0 * T_TOK + s0] = w0; ranks[i0 * T_TOK + s0] = 0;
    int s1 = atomicAdd(&counts[i1], 1);
    tokens[i1 * T_TOK + s1] = t; pairw[i1 * T_TOK + s1] = w1; ranks[i1 * T_TOK + s1] = 1;
  }
}

// prefix-scan + M-tile table (e, m0) over all experts
__global__ void k_scan(const int* __restrict__ counts, int* __restrict__ basep,
                       int* __restrict__ tile_e, int* __restrict__ tile_m,
                       int* __restrict__ ntile) {
  if (threadIdx.x == 0) {
    int s = 0, nt = 0;
    for (int e = 0; e < NEXP; e++) {
      basep[e] = s;
      for (int m0 = 0; m0 < counts[e]; m0 += BM) { tile_e[nt] = e; tile_m[nt] = m0; nt++; }
      s += counts[e];
    }
    *ntile = nt;
  }
}

// ================= bf16-weight fast path =================

// ---------- Kernel B: gathered gate+up GEMM + silu -> h (bf16) ----------
// Virtual-N: 128 virtual cols = 64 real cols x {gate,up} interleaved at 16.
// launch_bounds(256,3): VGPR 72 + AGPR 64 -> NO spill. (256,4) spilled (round 3).
// GRID ORDER: panel (x, fastest) x tile (y): the 22 consumers of one A-slice
// are consecutive/co-resident -> xnorm fetched ~once (round 4: tile-fastest
// order cost 22x xnorm re-read = 800 MB FETCH).
__global__ __launch_bounds__(256, 3) void k_gateup_bf16(
    const ushort_t* __restrict__ xnorm, const ushort_t* __restrict__ wgb,
    const ushort_t* __restrict__ wub, const int* __restrict__ tokens,
    const int* __restrict__ counts, const int* __restrict__ basep,
    const int* __restrict__ tile_e, const int* __restrict__ tile_m,
    const int* __restrict__ ntile, ushort_t* __restrict__ hbuf)
{
  const int bx = blockIdx.y;        // tile index
  if (bx >= *ntile) return;
  const int e = tile_e[bx];
  const int m0 = tile_m[bx];
  const int cnt = counts[e];
  const int r0 = blockIdx.x * 64;   // real I-column base (64 real cols/block)
  const int tid = threadIdx.x;

  __shared__ ushort_t As[BM * BK];   // unpadded: required by global_load_lds
  __shared__ ushort_t Bs[BN * BK];   // virtual-N tile (gate/up interleaved)

  const int lane = tid & 63;
  const int w = tid >> 6;
  // staging map: instr i covers LDS bytes (w*4+i)*1024 + lane*16
  // -> row = (w*4+i)*8 + (lane>>3); source chunk XOR-swizzled by row&7
  const int srow = lane >> 3;
  const int scol = ((lane & 7) ^ srow) * 8;

  const ushort_t* agp[4]; const ushort_t* bgp[4];
  #pragma unroll
  for (int i = 0; i < 4; i++) {
    const int rl = (w * 4 + i) * 8 + srow;
    const int slot = (m0 + rl < cnt) ? (m0 + rl) : (cnt - 1);
    const int tok = tokens[e * T_TOK + slot];
    agp[i] = xnorm + (size_t)tok * HDIM + scol;
    const int nrow = r0 + ((rl >> 5) << 4) + (rl & 15);   // real weight row
    const ushort_t* wsrc = ((rl >> 4) & 1) ? wub : wgb;   // 0=gate,1=up
    bgp[i] = wsrc + ((size_t)e * IDIM + nrow) * HDIM + scol;
  }

  const int wm = (w & 1) * 64;
  const int wn = (w >> 1) * 64;
  const int fr = lane & 15;
  const int fq = lane >> 4;
  const int sx = fr & 7;            // read-side XOR (row&7 == fr&7)

  f32x4 acc[4][4] = {};

  for (int k0 = 0; k0 < HDIM; k0 += BK) {
    #pragma unroll
    for (int i = 0; i < 4; i++) gll16(agp[i] + k0, &As[(w * 4 + i) * 512]);
    #pragma unroll
    for (int i = 0; i < 4; i++) gll16(bgp[i] + k0, &Bs[(w * 4 + i) * 512]);
    __syncthreads();
    #pragma unroll
    for (int kk = 0; kk < BK; kk += 32) {
      const int c0 = kk >> 3;       // base 16B-chunk index of this k-slice
      s16x8 af[4], bf[4];
      #pragma unroll
      for (int mi = 0; mi < 4; mi++)
        af[mi] = *(const s16x8*)(&As[(wm + mi * 16 + fr) * BK + (((c0 + fq) ^ sx) << 3)]);
      #pragma unroll
      for (int ni = 0; ni < 4; ni++)
        bf[ni] = *(const s16x8*)(&Bs[(wn + ni * 16 + fr) * BK + (((c0 + fq) ^ sx) << 3)]);
      #pragma unroll
      for (int mi = 0; mi < 4; mi++) {
        #pragma unroll
        for (int ni = 0; ni < 4; ni++)
          acc[mi][ni] = __builtin_amdgcn_mfma_f32_16x16x32_bf16(af[mi], bf[ni], acc[mi][ni], 0, 0, 0);
      }
    }
    __syncthreads();
  }

  // epilogue: ni even = gate, ni odd = up (same real col) -> wave-local silu
  const int hb = basep[e];
  #pragma unroll
  for (int mi = 0; mi < 4; mi++) {
    #pragma unroll
    for (int reg = 0; reg < 4; reg++) {
      const int rl = wm + mi * 16 + fq * 4 + reg;
      if (m0 + rl < cnt) {
        ushort_t* hrow = hbuf + (size_t)(hb + m0 + rl) * IDIM + r0 + (wn >> 1);
        #pragma unroll
        for (int nj = 0; nj < 2; nj++) {
          float g = acc[mi][2 * nj][reg];
          float u = acc[mi][2 * nj + 1][reg];
          float hv = (g / (1.0f + __expf(-g))) * u;
          hrow[nj * 16 + fr] = f2bf(hv);
        }
      }
    }
  }
}

// ---------- Kernel C: down GEMM, rank-split plain stores (NO atomics) ----------
// rank0 rows -> out directly; rank1 rows -> out_b; k_combine adds them.
// GRID ORDER: panel (x, fastest) x tile (y) -- same locality fix as gateup.
__global__ __launch_bounds__(256, 3) void k_down_bf16(
    const ushort_t* __restrict__ hbuf, const ushort_t* __restrict__ wdb,
    const int* __restrict__ tokens, const float* __restrict__ pairw,
    const int* __restrict__ ranks, const int* __restrict__ counts,
    const int* __restrict__ basep, const int* __restrict__ tile_e,
    const int* __restrict__ tile_m, const int* __restrict__ ntile,
    float* __restrict__ out, float* __restrict__ out_b)
{
  const int bx = blockIdx.y;        // tile index
  if (bx >= *ntile) return;
  const int e = tile_e[bx];
  const int m0 = tile_m[bx];
  const int cnt = counts[e];
  const int n0 = blockIdx.x * BN;
  const int tid = threadIdx.x;
  const int hb = basep[e];

  __shared__ ushort_t As[BM * BK];
  __shared__ ushort_t Bs[BN * BK];

  const int lane = tid & 63;
  const int w = tid >> 6;
  const int srow = lane >> 3;
  const int scol = ((lane & 7) ^ srow) * 8;   // bothsides swizzle, source side

  const ushort_t* agp[4]; const ushort_t* bgp[4];
  #pragma unroll
  for (int i = 0; i < 4; i++) {
    const int rl = (w * 4 + i) * 8 + srow;
    const int slot = (m0 + rl < cnt) ? (m0 + rl) : (cnt - 1);
    agp[i] = hbuf + (size_t)(hb + slot) * IDIM + scol;
    bgp[i] = wdb + ((size_t)e * HDIM + n0 + rl) * IDIM + scol;
  }

  const int wm = (w & 1) * 64;
  const int wn = (w >> 1) * 64;
  const int fr = lane & 15;
  const int fq = lane >> 4;
  const int sx = fr & 7;

  f32x4 acc[4][4] = {};

  for (int k0 = 0; k0 < IDIM; k0 += BK) {
    #pragma unroll
    for (int i = 0; i < 4; i++) gll16(agp[i] + k0, &As[(w * 4 + i) * 512]);
    #pragma unroll
    for (int i = 0; i < 4; i++) gll16(bgp[i] + k0, &Bs[(w * 4 + i) * 512]);
    __syncthreads();
    #pragma unroll
    for (int kk = 0; kk < BK; kk += 32) {
      const int c0 = kk >> 3;
      s16x8 af[4], bf[4];
      #pragma unroll
      for (int mi = 0; mi < 4; mi++)
        af[mi] = *(const s16x8*)(&As[(wm + mi * 16 + fr) * BK + (((c0 + fq) ^ sx) << 3)]);
      #pragma unroll
      for (int ni = 0; ni < 4; ni++)
        bf[ni] = *(const s16x8*)(&Bs[(wn + ni * 16 + fr) * BK + (((c0 + fq) ^ sx) << 3)]);
      #pragma unroll
      for (int mi = 0; mi < 4; mi++) {
        #pragma unroll
        for (int ni = 0; ni < 4; ni++)
          acc[mi][ni] = __builtin_amdgcn_mfma_f32_16x16x32_bf16(af[mi], bf[ni], acc[mi][ni], 0, 0, 0);
      }
    }
    __syncthreads();
  }

  #pragma unroll
  for (int mi = 0; mi < 4; mi++) {
    #pragma unroll
    for (int reg = 0; reg < 4; reg++) {
      const int rl = wm + mi * 16 + fq * 4 + reg;
      if (m0 + rl < cnt) {
        const int idx = e * T_TOK + m0 + rl;
        const int tok = tokens[idx];
        const float ww = pairw[idx];
        float* obase = ranks[idx] ? out_b : out;
        float* orow = obase + (size_t)tok * HDIM + n0;
        #pragma unroll
        for (int ni = 0; ni < 4; ni++)
          orow[wn + ni * 16 + fr] = ww * acc[mi][ni][reg];
      }
    }
  }
}

// ---------- Kernel D: out += out_b (both fully written) ----------
__global__ __launch_bounds__(256) void k_combine(float* __restrict__ out,
                                                 const float* __restrict__ outb, int n4) {
  int i = blockIdx.x * blockDim.x + threadIdx.x;
  const int stride = gridDim.x * blockDim.x;
  for (; i < n4; i += stride) {
    float4 a = ((const float4*)out)[i];
    float4 b = ((const float4*)outb)[i];
    a.x += b.x; a.y += b.y; a.z += b.z; a.w += b.w;
    ((float4*)out)[i] = a;
  }
}

// ================= fp32-weight fallback path (round-1 kernels) =================

__global__ __launch_bounds__(256, 2) void k_gateup_f32(
    const ushort_t* __restrict__ xnorm, const float* __restrict__ wg,
    const float* __restrict__ wu, const int* __restrict__ tokens,
    const int* __restrict__ counts, const int* __restrict__ basep,
    ushort_t* __restrict__ hbuf)
{
  const int e = blockIdx.z;
  const int cnt = counts[e];
  const int m0 = blockIdx.x * BM;
  if (m0 >= cnt) return;
  const int n0 = blockIdx.y * BN;
  const int tid = threadIdx.x;

  __shared__ ushort_t As[BM * LDK];
  __shared__ ushort_t Bgs[BN * LDK];
  __shared__ ushort_t Bus[BN * LDK];

  const int r = tid >> 1;
  const int col0 = (tid & 1) * 32;
  const int slot = (m0 + r < cnt) ? (m0 + r) : (cnt - 1);
  const int tok = tokens[e * T_TOK + slot];
  const ushort_t* asrc = xnorm + (size_t)tok * HDIM + col0;
  const float* gsrc = wg + ((size_t)e * IDIM + n0 + r) * HDIM + col0;
  const float* usrc = wu + ((size_t)e * IDIM + n0 + r) * HDIM + col0;

  const int lane = tid & 63;
  const int wid = tid >> 6;
  const int wm = (wid & 1) * 64;
  const int wn = (wid >> 1) * 64;
  const int fr = lane & 15;
  const int fq = lane >> 4;

  f32x4 accg[4][4] = {};
  f32x4 accu[4][4] = {};

  for (int k0 = 0; k0 < HDIM; k0 += BK) {
    #pragma unroll
    for (int i = 0; i < 4; i++) {
      uint4 v = *(const uint4*)(asrc + k0 + i * 8);
      *(uint4*)(&As[r * LDK + col0 + i * 8]) = v;
    }
    #pragma unroll
    for (int i = 0; i < 4; i++) {
      float4 f0 = *(const float4*)(gsrc + k0 + i * 8);
      float4 f1 = *(const float4*)(gsrc + k0 + i * 8 + 4);
      union { ushort_t us[8]; uint4 v; } p;
      p.us[0]=f2bf(f0.x); p.us[1]=f2bf(f0.y); p.us[2]=f2bf(f0.z); p.us[3]=f2bf(f0.w);
      p.us[4]=f2bf(f1.x); p.us[5]=f2bf(f1.y); p.us[6]=f2bf(f1.z); p.us[7]=f2bf(f1.w);
      *(uint4*)(&Bgs[r * LDK + col0 + i * 8]) = p.v;
    }
    #pragma unroll
    for (int i = 0; i < 4; i++) {
      float4 f0 = *(const float4*)(usrc + k0 + i * 8);
      float4 f1 = *(const float4*)(usrc + k0 + i * 8 + 4);
      union { ushort_t us[8]; uint4 v; } p;
      p.us[0]=f2bf(f0.x); p.us[1]=f2bf(f0.y); p.us[2]=f2bf(f0.z); p.us[3]=f2bf(f0.w);
      p.us[4]=f2bf(f1.x); p.us[5]=f2bf(f1.y); p.us[6]=f2bf(f1.z); p.us[7]=f2bf(f1.w);
      *(uint4*)(&Bus[r * LDK + col0 + i * 8]) = p.v;
    }
    __syncthreads();
    #pragma unroll
    for (int kk = 0; kk < BK; kk += 32) {
      s16x8 af[4], bg[4], bu[4];
      #pragma unroll
      for (int mi = 0; mi < 4; mi++)
        af[mi] = *(const s16x8*)(&As[(wm + mi * 16 + fr) * LDK + kk + fq * 8]);
      #pragma unroll
      for (int ni = 0; ni < 4; ni++) {
        bg[ni] = *(const s16x8*)(&Bgs[(wn + ni * 16 + fr) * LDK + kk + fq * 8]);
        bu[ni] = *(const s16x8*)(&Bus[(wn + ni * 16 + fr) * LDK + kk + fq * 8]);
      }
      #pragma unroll
      for (int mi = 0; mi < 4; mi++) {
        #pragma unroll
        for (int ni = 0; ni < 4; ni++) {
          accg[mi][ni] = __builtin_amdgcn_mfma_f32_16x16x32_bf16(af[mi], bg[ni], accg[mi][ni], 0, 0, 0);
          accu[mi][ni] = __builtin_amdgcn_mfma_f32_16x16x32_bf16(af[mi], bu[ni], accu[mi][ni], 0, 0, 0);
        }
      }
    }
    __syncthreads();
  }

  const int hb = basep[e];
  #pragma unroll
  for (int mi = 0; mi < 4; mi++) {
    #pragma unroll
    for (int reg = 0; reg < 4; reg++) {
      const int rl = wm + mi * 16 + fq * 4 + reg;
      if (m0 + rl < cnt) {
        ushort_t* hrow = hbuf + (size_t)(hb + m0 + rl) * IDIM + n0;
        #pragma unroll
        for (int ni = 0; ni < 4; ni++) {
          float g = accg[mi][ni][reg];
          float u = accu[mi][ni][reg];
          float hv = (g / (1.0f + __expf(-g))) * u;
          hrow[wn + ni * 16 + fr] = f2bf(hv);
        }
      }
    }
  }
}

__global__ __launch_bounds__(256, 2) void k_down_f32(
    const ushort_t* __restrict__ hbuf, const float* __restrict__ wd,
    const int* __restrict__ tokens, const float* __restrict__ pairw,
    const int* __restrict__ counts, const int* __restrict__ basep,
    float* __restrict__ out)
{
  const int e = blockIdx.z;
  const int cnt = counts[e];
  const int m0 = blockIdx.x * BM;
  if (m0 >= cnt) return;
  const int n0 = blockIdx.y * BN;
  const int tid = threadIdx.x;
  const int hb = basep[e];

  __shared__ ushort_t As[BM * LDK];
  __shared__ ushort_t Bs[BN * LDK];

  const int r = tid >> 1;
  const int col0 = (tid & 1) * 32;
  const int slot = (m0 + r < cnt) ? (m0 + r) : (cnt - 1);
  const ushort_t* asrc = hbuf + (size_t)(hb + slot) * IDIM + col0;
  const float* bsrc = wd + ((size_t)e * HDIM + n0 + r) * IDIM + col0;

  const int lane = tid & 63;
  const int wid = tid >> 6;
  const int wm = (wid & 1) * 64;
  const int wn = (wid >> 1) * 64;
  const int fr = lane & 15;
  const int fq = lane >> 4;

  f32x4 acc[4][4] = {};

  for (int k0 = 0; k0 < IDIM; k0 += BK) {
    #pragma unroll
    for (int i = 0; i < 4; i++) {
      uint4 v = *(const uint4*)(asrc + k0 + i * 8);
      *(uint4*)(&As[r * LDK + col0 + i * 8]) = v;
    }
    #pragma unroll
    for (int i = 0; i < 4; i++) {
      float4 f0 = *(const float4*)(bsrc + k0 + i * 8);
      float4 f1 = *(const float4*)(bsrc + k0 + i * 8 + 4);
      union { ushort_t us[8]; uint4 v; } p;
      p.us[0]=f2bf(f0.x); p.us[1]=f2bf(f0.y); p.us[2]=f2bf(f0.z); p.us[3]=f2bf(f0.w);
      p.us[4]=f2bf(f1.x); p.us[5]=f2bf(f1.y); p.us[6]=f2bf(f1.z); p.us[7]=f2bf(f1.w);
      *(uint4*)(&Bs[r * LDK + col0 + i * 8]) = p.v;
    }
    __syncthreads();
    #pragma unroll
    for (int kk = 0; kk < BK; kk += 32) {
      s16x8 af[4], bf[4];
      #pragma unroll
      for (int mi = 0; mi < 4; mi++)
        af[mi] = *(const s16x8*)(&As[(wm + mi * 16 + fr) * LDK + kk + fq * 8]);
      #pragma unroll
      for (int ni = 0; ni < 4; ni++)
        bf[ni] = *(const s16x8*)(&Bs[(wn + ni * 16 + fr) * LDK + kk + fq * 8]);
      #pragma unroll
      for (int mi = 0; mi < 4; mi++) {
        #pragma unroll
        for (int ni = 0; ni < 4; ni++)
          acc[mi][ni] = __builtin_amdgcn_mfma_f32_16x16x32_bf16(af[mi], bf[ni], acc[mi][ni], 0, 0, 0);
      }
    }
    __syncthreads();
  }

  #pragma unroll
  for (int mi = 0; mi < 4; mi++) {
    #pragma unroll
    for (int reg = 0; reg < 4; reg++) {
      const int rl = wm + mi * 16 + fq * 4 + reg;
      if (m0 + rl < cnt) {
        const int tok = tokens[e * T_TOK + m0 + rl];
        const float ww = pairw[e * T_TOK + m0 + rl];
        float* orow = out + (size_t)tok * HDIM + n0;
        #pragma unroll
        for (int ni = 0; ni < 4; ni++)
          atomicAdd(&orow[wn + ni * 16 + fr], ww * acc[mi][ni][reg]);
      }
    }
  }
}

extern "C" void kernel_launch(void* const* d_in, const int* in_sizes, int n_in,
                              void* d_out, int out_size, void* d_ws, size_t ws_size,
                              hipStream_t stream)
{
  (void)in_sizes; (void)n_in;
  const float* x    = (const float*)d_in[0];
  const float* rmsw = (const float*)d_in[1];
  const float* rw   = (const float*)d_in[2];
  const float* wg   = (const float*)d_in[3];
  const float* wu   = (const float*)d_in[4];
  const float* wd   = (const float*)d_in[5];
  float* out = (float*)d_out;
  float* logits_out = out + (size_t)T_TOK * HDIM;

  const size_t WB = (size_t)NEXP * IDIM * HDIM * 2;   // 46,137,344 B per bf16 weight
  const size_t HB = (size_t)2 * T_TOK * IDIM * 2;     // 46,137,344 B hbuf
  const size_t XB = (size_t)T_TOK * HDIM * 2;         // 33,554,432 B xnorm
  const size_t BOOK = 2048 + 3 * (size_t)NEXP * T_TOK * 4;  // counts/basep/tiles/tokens/pairw/ranks

  char* ws = (char*)d_ws;
  int* counts  = (int*)ws;
  int* basep   = (int*)(ws + 256);
  int* ntile   = (int*)(ws + 320);
  int* tile_e  = (int*)(ws + 384);                       // 136*4 B
  int* tile_m  = (int*)(ws + 1024);                      // 136*4 B
  int* tokens  = (int*)(ws + 2048);
  float* pairw = (float*)(ws + 2048 + (size_t)NEXP * T_TOK * 4);
  int* ranks   = (int*)(ws + 2048 + 2 * (size_t)NEXP * T_TOK * 4);

  hipMemsetAsync(d_ws, 0, 512, stream);

  const size_t NEED = BOOK + HB + 2 * WB + ((WB > XB) ? WB : XB) + 4096;
  const int n8 = (int)((size_t)NEXP * IDIM * HDIM / 8);  // elems/8 per weight tensor

  if (ws_size >= NEED) {
    // fast path: bf16 weights + global_load_lds + rank-split combine (no atomics)
    ushort_t* hbuf  = (ushort_t*)(ws + BOOK);
    ushort_t* wgb   = (ushort_t*)(ws + BOOK + HB);
    ushort_t* wub   = (ushort_t*)(ws + BOOK + HB + WB);
    ushort_t* xnorm = (ushort_t*)(ws + BOOK + HB + 2 * WB);
    ushort_t* wdb   = (ushort_t*)(ws + BOOK + HB + 2 * WB);  // aliases xnorm (used after)
    float* out_b    = (float*)(ws + BOOK + HB);              // overlays wgb/wub (dead in down phase); 67MB <= 92MB

    k_cast<<<(n8 + 255) / 256, 256, 0, stream>>>(wg, wgb, n8);
    k_cast<<<(n8 + 255) / 256, 256, 0, stream>>>(wu, wub, n8);
    k_rms_router<<<T_TOK, 256, 0, stream>>>(x, rmsw, rw, xnorm, logits_out,
                                            counts, tokens, pairw, ranks);
    k_scan<<<1, 64, 0, stream>>>(counts, basep, tile_e, tile_m, ntile);
    // panel-fastest grid: 22 panels x tile table
    k_gateup_bf16<<<dim3(IDIM / 64, NTILE_MAX), 256, 0, stream>>>(
        xnorm, wgb, wub, tokens, counts, basep, tile_e, tile_m, ntile, hbuf);
    k_cast<<<(n8 + 255) / 256, 256, 0, stream>>>(wd, wdb, n8);  // overwrites xnorm (done)
    k_down_bf16<<<dim3(HDIM / BN, NTILE_MAX), 256, 0, stream>>>(
        hbuf, wdb, tokens, pairw, ranks, counts, basep, tile_e, tile_m, ntile,
        out, out_b);
    k_combine<<<2048, 256, 0, stream>>>(out, out_b, (int)((size_t)T_TOK * HDIM / 4));
  } else {
    // fallback: round-1 fp32-staging path (~80 MB ws)
    ushort_t* xnorm = (ushort_t*)(ws + BOOK);
    ushort_t* hbuf  = (ushort_t*)(ws + BOOK + XB);

    hipMemsetAsync(d_out, 0, (size_t)out_size * sizeof(float), stream);
    k_rms_router<<<T_TOK, 256, 0, stream>>>(x, rmsw, rw, xnorm, logits_out,
                                            counts, tokens, pairw, ranks);
    k_scan<<<1, 64, 0, stream>>>(counts, basep, tile_e, tile_m, ntile);
    k_gateup_f32<<<dim3(T_TOK / BM, IDIM / BN, NEXP), 256, 0, stream>>>(
        xnorm, wg, wu, tokens, counts, basep, hbuf);
    k_down_f32<<<dim3(T_TOK / BM, HDIM / BN, NEXP), 256, 0, stream>>>(
        hbuf, wd, tokens, pairw, counts, basep, out);
  }
}